// Round 5
// baseline (219.146 us; speedup 1.0000x reference)
//
#include <hip/hip_runtime.h>

#define NN 4096
#define NHEADS 4
#define HID 64
#define INDIM 256

using short8 = __attribute__((ext_vector_type(8))) short;
using f32x4  = __attribute__((ext_vector_type(4))) float;

union f32u { float f; unsigned int u; };
union i4s8 { int4 i; short8 s; };

__device__ __forceinline__ float bf2f(unsigned short s) {
  f32u x; x.u = ((unsigned int)s) << 16; return x.f;
}
__device__ __forceinline__ unsigned short f2bf(float f) {
  f32u x; x.f = f;
  unsigned int r = x.u + 0x7fffu + ((x.u >> 16) & 1u);
  return (unsigned short)(r >> 16);
}
// packed f32x2 -> bf16x2 (RNE, same as f2bf) in one instruction
__device__ __forceinline__ unsigned int cvtpk(float lo, float hi) {
  unsigned int r;
  asm("v_cvt_pk_bf16_f32 %0, %1, %2" : "=v"(r) : "v"(lo), "v"(hi));
  return r;
}

// overloaded external-input loaders
__device__ __forceinline__ float ld(const unsigned short* p, size_t i) { return bf2f(p[i]); }
__device__ __forceinline__ float ld(const float* p, size_t i) { return p[i]; }
// vectorized 8-element loader (16B for bf16, 32B for fp32) — p must be 8-elem aligned
__device__ __forceinline__ void ld8(const unsigned short* p, float* out) {
  short8 v = *(const short8*)p;
#pragma unroll
  for (int j = 0; j < 8; j++) out[j] = bf2f((unsigned short)v[j]);
}
__device__ __forceinline__ void ld8(const float* p, float* out) {
  float4 a = *(const float4*)p;
  float4 b = *(const float4*)(p + 4);
  out[0] = a.x; out[1] = a.y; out[2] = a.z; out[3] = a.w;
  out[4] = b.x; out[5] = b.y; out[6] = b.z; out[7] = b.w;
}

// ---------------- Probe: classify input dtypes at runtime (parallel, 256 threads).
__global__ __launch_bounds__(256) void k_probe(const void* hv, const void* adjv, int* flags) {
  __shared__ int s_bad, s_at;
  const int tid = threadIdx.x;
  if (tid == 0) { s_bad = 0; s_at = 0; }
  __syncthreads();
  const unsigned short* hu = (const unsigned short*)hv;
  float v = bf2f(hu[tid]);
  if (!(v > -1000.f && v < 1000.f)) atomicOr(&s_bad, 1);
  const unsigned int* au = (const unsigned int*)adjv;
  unsigned int wv = au[tid];
  if ((wv & 0xFFFFu) == 0x3F80u) atomicOr(&s_at, 2);
  else if (wv == 0x3F800000u) atomicOr(&s_at, 1);
  __syncthreads();
  if (tid == 0) {
    flags[0] = s_bad ? 0 : 1;
    int at = s_at;
    flags[1] = (at & 2) ? 2 : (at & 1);
  }
}

// ---------------- K0: adj -> bitmask bytes bm[i][j>>3]
__global__ __launch_bounds__(256) void k_bm(const void* adjv, const int* __restrict__ flags,
                                            unsigned char* __restrict__ bm) {
  const int at = flags[1];
  const int i = blockIdx.x;
#pragma unroll
  for (int rep = 0; rep < 2; rep++) {
    int jb = threadIdx.x + rep * 256;
    unsigned int b = 0;
    if (at == 0) {
      const int4* arow = (const int4*)((const int*)adjv + (size_t)i * NN);
      int4 a0 = arow[jb * 2 + 0];
      int4 a1 = arow[jb * 2 + 1];
      b |= (a0.x > 0) ? 1u : 0u;  b |= (a0.y > 0) ? 2u : 0u;
      b |= (a0.z > 0) ? 4u : 0u;  b |= (a0.w > 0) ? 8u : 0u;
      b |= (a1.x > 0) ? 16u : 0u; b |= (a1.y > 0) ? 32u : 0u;
      b |= (a1.z > 0) ? 64u : 0u; b |= (a1.w > 0) ? 128u : 0u;
    } else if (at == 1) {
      const float* arow = (const float*)adjv + (size_t)i * NN + jb * 8;
      for (int t = 0; t < 8; t++) b |= (arow[t] > 0.5f) ? (1u << t) : 0u;
    } else {
      const unsigned short* arow = (const unsigned short*)adjv + (size_t)i * NN + jb * 8;
      for (int t = 0; t < 8; t++) b |= (bf2f(arow[t]) > 0.5f) ? (1u << t) : 0u;
    }
    bm[(size_t)i * 512 + jb] = (unsigned char)b;
  }
}

// ---------------- K1: wh = h@Wh + bWh, emit packed bf16 B-fragments + s_src(+a_b)/s_dst
// v2: 4 rows/block (grid 1024 -> 16 waves/CU), 8-k blocked inner loop with short8 h loads.
// Load instrs/thread: 2304 -> 384 (6x); W loads stay scalar but lane-coalesced.
template <typename T>
__device__ __forceinline__ void wh_body(const T* h, const T* Wh, const T* bWh,
    const T* a_src, const T* a_dst, const T* a_b,
    unsigned short* Bp1, float* ssrc1, float* sdst1) {
  const int head = threadIdx.x >> 6;
  const int d = threadIdx.x & 63;
  const int i0 = blockIdx.x * 4;
  const T* W = Wh + (size_t)(head * INDIM) * HID + d;
  float acc[4];
  float bv = ld(bWh, head * HID + d);
#pragma unroll
  for (int r = 0; r < 4; r++) acc[r] = bv;
  for (int kb = 0; kb < INDIM / 8; kb++) {
    float wv[8];
#pragma unroll
    for (int j = 0; j < 8; j++) wv[j] = ld(W, (size_t)(kb * 8 + j) * HID);
#pragma unroll
    for (int r = 0; r < 4; r++) {
      float hf[8];
      ld8(h + (size_t)(i0 + r) * INDIM + kb * 8, hf);
#pragma unroll
      for (int j = 0; j < 8; j++) acc[r] = fmaf(hf[j], wv[j], acc[r]);
    }
  }
  float asv = ld(a_src, head * HID + d);
  float adv = ld(a_dst, head * HID + d);
  float abv = ld(a_b, head);
#pragma unroll
  for (int r = 0; r < 4; r++) {
    float ps = acc[r] * asv, pd = acc[r] * adv;
#pragma unroll
    for (int o = 32; o > 0; o >>= 1) { ps += __shfl_xor(ps, o); pd += __shfl_xor(pd, o); }
    int i = i0 + r;
    if (d == 0) { ssrc1[head * NN + i] = ps + abv; sdst1[head * NN + i] = pd; }
    int kb = i >> 5, quad = (i >> 3) & 3, jj = i & 7;
    int ln = quad * 16 + (d & 15), tt = d >> 4;
    Bp1[((((size_t)head * 128 + kb) * 4 + tt) * 64 + ln) * 8 + jj] = f2bf(acc[r]);
  }
}
__global__ __launch_bounds__(256) void k_wh(const void* h, const void* Wh, const void* bWh,
    const void* a_src, const void* a_dst, const void* a_b, const int* __restrict__ flags,
    unsigned short* Bp1, float* ssrc1, float* sdst1) {
  if (flags[0])
    wh_body<unsigned short>((const unsigned short*)h, (const unsigned short*)Wh,
        (const unsigned short*)bWh, (const unsigned short*)a_src,
        (const unsigned short*)a_dst, (const unsigned short*)a_b, Bp1, ssrc1, sdst1);
  else
    wh_body<float>((const float*)h, (const float*)Wh, (const float*)bWh, (const float*)a_src,
        (const float*)a_dst, (const float*)a_b, Bp1, ssrc1, sdst1);
}

// ---------------- K2-new: layer-1 attention. Grid 256 = 128 rowblocks(32 rows) x 2 kb-halves.
// 1024 thr = 16 waves = 4 heads x 4 slices(16 kb). Two A-frags/wave share every B load.
// launch_bounds(1024,4): VGPR cap 128 -> no spill (round-2's (512,6) cap 80 caused 275 MB
// of scratch traffic).
__global__ __launch_bounds__(1024, 4) void k_att1s(
    const unsigned char* __restrict__ bm, const float* __restrict__ ssrc,
    const float* __restrict__ sdst, const short8* __restrict__ Bp,
    float* __restrict__ part, float* __restrict__ partl) {
  const int rb = blockIdx.x & 127;
  const int half = blockIdx.x >> 7;
  const int tid = threadIdx.x;
  const int w = tid >> 6;
  const int head = w & 3;
  const int sl = w >> 2;  // 0..3: 16-kb slice within this half
  const int lane = tid & 63;
  const int r15 = lane & 15, quad = lane >> 4;
  const int row0 = rb * 32 + r15;
  const int row1 = row0 + 16;
  const float si0 = ssrc[head * NN + row0];
  const float si1 = ssrc[head * NN + row1];
  const unsigned char* bmr0 = bm + (size_t)row0 * 512;
  const unsigned char* bmr1 = bm + (size_t)row1 * 512;
  const float* sd = sdst + head * NN;
  const short8* Bh = Bp + (size_t)head * 128 * 4 * 64;
  f32x4 acc0[4], acc1[4];
#pragma unroll
  for (int t = 0; t < 4; t++) { acc0[t] = (f32x4){0,0,0,0}; acc1[t] = (f32x4){0,0,0,0}; }
  float ls0 = 0.f, ls1 = 0.f;
  const int kb0 = half * 64 + sl * 16;
  for (int g = 0; g < 4; g++) {          // 4 kb per group, bm fetched as int4
    const int kbg = kb0 + g * 4;
    int4 u0 = *(const int4*)(bmr0 + kbg * 4);
    int4 u1 = *(const int4*)(bmr1 + kbg * 4);
    int wd0[4] = {u0.x, u0.y, u0.z, u0.w};
    int wd1[4] = {u1.x, u1.y, u1.z, u1.w};
#pragma unroll
    for (int kk = 0; kk < 4; kk++) {
      const int kb = kbg + kk;
      const int j0 = kb * 32 + quad * 8;
      float4 q0 = *(const float4*)(sd + j0);
      float4 q1 = *(const float4*)(sd + j0 + 4);
      float sdv[8] = {q0.x, q0.y, q0.z, q0.w, q1.x, q1.y, q1.z, q1.w};
      unsigned int bits0 = (((unsigned int)wd0[kk]) >> (quad * 8)) & 0xffu;
      unsigned int bits1 = (((unsigned int)wd1[kk]) >> (quad * 8)) & 0xffu;
      float pe0[8], pe1[8];
#pragma unroll
      for (int jj = 0; jj < 8; jj++) {
        float t0 = si0 + sdv[jj];
        float e0 = __expf(fmaxf(t0, 0.2f * t0));
        pe0[jj] = ((bits0 >> jj) & 1u) ? e0 : 0.f;
        ls0 += pe0[jj];
        float t1 = si1 + sdv[jj];
        float e1 = __expf(fmaxf(t1, 0.2f * t1));
        pe1[jj] = ((bits1 >> jj) & 1u) ? e1 : 0.f;
        ls1 += pe1[jj];
      }
      i4s8 a0, a1;
      a0.i.x = cvtpk(pe0[0], pe0[1]); a0.i.y = cvtpk(pe0[2], pe0[3]);
      a0.i.z = cvtpk(pe0[4], pe0[5]); a0.i.w = cvtpk(pe0[6], pe0[7]);
      a1.i.x = cvtpk(pe1[0], pe1[1]); a1.i.y = cvtpk(pe1[2], pe1[3]);
      a1.i.z = cvtpk(pe1[4], pe1[5]); a1.i.w = cvtpk(pe1[6], pe1[7]);
      const short8* Bk = Bh + (size_t)kb * 256 + lane;
      short8 bt[4];
      bt[0] = Bk[0]; bt[1] = Bk[64]; bt[2] = Bk[128]; bt[3] = Bk[192];
#pragma unroll
      for (int t = 0; t < 4; t++) {
        acc0[t] = __builtin_amdgcn_mfma_f32_16x16x32_bf16(a0.s, bt[t], acc0[t], 0, 0, 0);
        acc1[t] = __builtin_amdgcn_mfma_f32_16x16x32_bf16(a1.s, bt[t], acc1[t], 0, 0, 0);
      }
    }
  }
  ls0 += __shfl_xor(ls0, 16); ls0 += __shfl_xor(ls0, 32);
  ls1 += __shfl_xor(ls1, 16); ls1 += __shfl_xor(ls1, 32);
  // combine 4 slices via 8 slots (head x 2): slices {2,3} write, {0,1} add; out sums pair.
  __shared__ float accs[8][16][66];
  __shared__ float lsh[8][16];
#define DOPASS(AC, LSV, PASS)                                                  \
  do {                                                                         \
    if (sl >= 2) {                                                             \
      const int slot = head * 2 + (sl - 2);                                    \
      if (lane < 16) lsh[slot][lane] = (LSV);                                  \
      _Pragma("unroll") for (int t = 0; t < 4; t++)                            \
        _Pragma("unroll") for (int gg = 0; gg < 4; gg++)                       \
          accs[slot][quad * 4 + gg][t * 16 + r15] = (AC)[t][gg];               \
    }                                                                          \
    __syncthreads();                                                           \
    if (sl < 2) {                                                              \
      const int slot = head * 2 + sl;                                          \
      if (lane < 16) lsh[slot][lane] += (LSV);                                 \
      _Pragma("unroll") for (int t = 0; t < 4; t++)                            \
        _Pragma("unroll") for (int gg = 0; gg < 4; gg++)                       \
          accs[slot][quad * 4 + gg][t * 16 + r15] += (AC)[t][gg];              \
    }                                                                          \
    __syncthreads();                                                           \
    _Pragma("unroll") for (int idx = tid; idx < 4096; idx += 1024) {           \
      int r = idx >> 8, hc = idx & 255;                                        \
      int hh = hc >> 6, col = hc & 63;                                         \
      part[((size_t)half * NN + rb * 32 + (PASS) * 16 + r) * 256 + hc] =       \
          accs[hh * 2][r][col] + accs[hh * 2 + 1][r][col];                     \
    }                                                                          \
    if (tid < 64)                                                              \
      partl[((size_t)half * 4 + (tid >> 4)) * NN + rb * 32 + (PASS) * 16 +     \
            (tid & 15)] = lsh[(tid >> 4) * 2][tid & 15] +                      \
                          lsh[(tid >> 4) * 2 + 1][tid & 15];                   \
    __syncthreads();                                                           \
  } while (0)
  DOPASS(acc0, ls0, 0);
  DOPASS(acc1, ls1, 1);
#undef DOPASS
}

// ---------------- K2-fin: sum the 2 kb-half partials, normalize, elu, pack bf16.
__global__ __launch_bounds__(256) void k_att1f(const float* __restrict__ part,
    const float* __restrict__ partl, unsigned short* __restrict__ x2) {
  const int idx = blockIdx.x * 256 + threadIdx.x;  // 262144 = 4096 rows x 64 col-quads
  const int row = idx >> 6;
  const int c4 = (idx & 63) * 4;
  const int head = c4 >> 6;
  const size_t off = (size_t)row * 256 + c4;
  float4 p0 = *(const float4*)(part + off);
  float4 p1 = *(const float4*)(part + (size_t)NN * 256 + off);
  float lt = partl[(size_t)head * NN + row] + partl[(size_t)(4 + head) * NN + row];
  float rl = (lt > 0.f) ? 1.f / lt : 0.f;
  float v0 = (p0.x + p1.x) * rl, v1 = (p0.y + p1.y) * rl;
  float v2 = (p0.z + p1.z) * rl, v3 = (p0.w + p1.w) * rl;
  v0 = v0 > 0.f ? v0 : __expf(v0) - 1.f;
  v1 = v1 > 0.f ? v1 : __expf(v1) - 1.f;
  v2 = v2 > 0.f ? v2 : __expf(v2) - 1.f;
  v3 = v3 > 0.f ? v3 : __expf(v3) - 1.f;
  uint2 st; st.x = cvtpk(v0, v1); st.y = cvtpk(v2, v3);
  *(uint2*)(x2 + off) = st;
}

// ---------------- K2-old (fallback if workspace too small for partials)
__global__ __launch_bounds__(1024) void k_att1(
    const unsigned char* __restrict__ bm, const float* __restrict__ ssrc,
    const float* __restrict__ sdst, const short8* __restrict__ Bp,
    unsigned short* __restrict__ x2) {
  const int rb = blockIdx.x;
  const int tid = threadIdx.x;
  const int w = tid >> 6;
  const int head = w & 3;
  const int slice = w >> 2;
  const int lane = tid & 63;
  const int r15 = lane & 15, quad = lane >> 4;
  const int row = rb * 16 + r15;
  const float si = ssrc[head * NN + row];
  const unsigned char* bmrow = bm + (size_t)row * 512;
  const float* sd = sdst + head * NN;
  const short8* Bh = Bp + (size_t)head * 128 * 4 * 64;
  f32x4 acc0 = {0, 0, 0, 0}, acc1 = {0, 0, 0, 0}, acc2 = {0, 0, 0, 0}, acc3 = {0, 0, 0, 0};
  float lsum = 0.f;
  const int kb0 = slice * 32;
  for (int kb = kb0; kb < kb0 + 32; kb++) {
    const int j0 = kb * 32 + quad * 8;
    unsigned int bits = bmrow[kb * 4 + quad];
    float4 q0 = *(const float4*)(sd + j0);
    float4 q1 = *(const float4*)(sd + j0 + 4);
    float sdv[8] = {q0.x, q0.y, q0.z, q0.w, q1.x, q1.y, q1.z, q1.w};
    short8 af;
#pragma unroll
    for (int jj = 0; jj < 8; jj++) {
      float t = si + sdv[jj];
      float lr = fmaxf(t, 0.2f * t);
      float e = __expf(lr);
      float pe = ((bits >> jj) & 1u) ? e : 0.0f;
      lsum += pe;
      af[jj] = (short)f2bf(pe);
    }
    const short8* Bk = Bh + (size_t)kb * 256 + lane;
    short8 b0 = Bk[0], b1 = Bk[64], b2 = Bk[128], b3 = Bk[192];
    acc0 = __builtin_amdgcn_mfma_f32_16x16x32_bf16(af, b0, acc0, 0, 0, 0);
    acc1 = __builtin_amdgcn_mfma_f32_16x16x32_bf16(af, b1, acc1, 0, 0, 0);
    acc2 = __builtin_amdgcn_mfma_f32_16x16x32_bf16(af, b2, acc2, 0, 0, 0);
    acc3 = __builtin_amdgcn_mfma_f32_16x16x32_bf16(af, b3, acc3, 0, 0, 0);
  }
  lsum += __shfl_xor(lsum, 16);
  lsum += __shfl_xor(lsum, 32);
  __shared__ float accs[8][16][66];
  __shared__ float ls[8][16];
  if (slice >= 2) {
    const int slot = w - 8;
    if (lane < 16) ls[slot][lane] = lsum;
#pragma unroll
    for (int g = 0; g < 4; g++) {
      int r = quad * 4 + g;
      accs[slot][r][ 0 + r15] = acc0[g];
      accs[slot][r][16 + r15] = acc1[g];
      accs[slot][r][32 + r15] = acc2[g];
      accs[slot][r][48 + r15] = acc3[g];
    }
  }
  __syncthreads();
  if (slice < 2) {
    const int slot = w;
    if (lane < 16) ls[slot][lane] += lsum;
#pragma unroll
    for (int g = 0; g < 4; g++) {
      int r = quad * 4 + g;
      accs[slot][r][ 0 + r15] += acc0[g];
      accs[slot][r][16 + r15] += acc1[g];
      accs[slot][r][32 + r15] += acc2[g];
      accs[slot][r][48 + r15] += acc3[g];
    }
  }
  __syncthreads();
#pragma unroll
  for (int c = tid; c < 4096; c += 1024) {
    int r = c >> 8, hc = c & 255;
    int hh = hc >> 6, col = hc & 63;
    float s = accs[hh][r][col] + accs[hh + 4][r][col];
    float lt = ls[hh][r] + ls[hh + 4][r];
    float v = (lt > 0.f) ? s / lt : 0.f;
    v = v > 0.f ? v : __expf(v) - 1.f;
    x2[(size_t)(rb * 16 + r) * 256 + hc] = f2bf(v);
  }
}

// ---------------- K3: wo = x2@Wo + bWo (8-k blocked, short8 x2 loads)
template <typename T>
__device__ __forceinline__ void wo_body(const unsigned short* x2, const T* Wo, const T* bWo,
    const T* ao_src, const T* ao_dst, const T* ao_b,
    unsigned short* Bp2, float* ssrc2, float* sdst2) {
  const int w = threadIdx.x >> 6, d = threadIdx.x & 63;
  const int i = blockIdx.x * 4 + w;
  const short8* xr8 = (const short8*)(x2 + (size_t)i * 256);
  float acc = ld(bWo, d);
  for (int kb = 0; kb < 32; kb++) {
    float wv[8];
#pragma unroll
    for (int j = 0; j < 8; j++) wv[j] = ld(Wo, (size_t)(kb * 8 + j) * 64 + d);
    short8 xv = xr8[kb];
#pragma unroll
    for (int j = 0; j < 8; j++)
      acc = fmaf(bf2f((unsigned short)xv[j]), wv[j], acc);
  }
  float ps = acc * ld(ao_src, d);
  float pd = acc * ld(ao_dst, d);
#pragma unroll
  for (int o = 32; o > 0; o >>= 1) { ps += __shfl_xor(ps, o); pd += __shfl_xor(pd, o); }
  if (d == 0) { ssrc2[i] = ps + ld(ao_b, 0); sdst2[i] = pd; }
  int kb = i >> 5, quad = (i >> 3) & 3, jj = i & 7;
  int ln = quad * 16 + (d & 15), tt = d >> 4;
  Bp2[(((size_t)kb * 4 + tt) * 64 + ln) * 8 + jj] = f2bf(acc);
}
__global__ __launch_bounds__(256) void k_wo(const unsigned short* __restrict__ x2,
    const void* Wo, const void* bWo, const void* ao_src, const void* ao_dst, const void* ao_b,
    const int* __restrict__ flags, unsigned short* Bp2, float* ssrc2, float* sdst2) {
  if (flags[0])
    wo_body<unsigned short>(x2, (const unsigned short*)Wo, (const unsigned short*)bWo,
        (const unsigned short*)ao_src, (const unsigned short*)ao_dst,
        (const unsigned short*)ao_b, Bp2, ssrc2, sdst2);
  else
    wo_body<float>(x2, (const float*)Wo, (const float*)bWo, (const float*)ao_src,
        (const float*)ao_dst, (const float*)ao_b, Bp2, ssrc2, sdst2);
}

// ---------------- K4: layer-2 attention (1 head), 16 rows/block, 16-way j-split.
__global__ __launch_bounds__(1024) void k_att2(
    const unsigned char* __restrict__ bm, const float* __restrict__ ssrc,
    const float* __restrict__ sdst, const short8* __restrict__ Bp,
    const int* __restrict__ flags, void* __restrict__ outv) {
  const int rb = blockIdx.x;
  const int tid = threadIdx.x;
  const int w = tid >> 6;  // j-slice 0..15
  const int lane = tid & 63;
  const int r15 = lane & 15, quad = lane >> 4;
  const int row = rb * 16 + r15;
  const float si = ssrc[row];
  const unsigned char* bmrow = bm + (size_t)row * 512;
  f32x4 acc0 = {0, 0, 0, 0}, acc1 = {0, 0, 0, 0}, acc2 = {0, 0, 0, 0}, acc3 = {0, 0, 0, 0};
  float lsum = 0.f;
  const int kb0 = w * 8;
#pragma unroll
  for (int g = 0; g < 2; g++) {
    int4 ubm = *(const int4*)(bmrow + (kb0 + g * 4) * 4);
    int wds[4] = {ubm.x, ubm.y, ubm.z, ubm.w};
#pragma unroll
    for (int kk = 0; kk < 4; kk++) {
      const int kb = kb0 + g * 4 + kk;
      const int j0 = kb * 32 + quad * 8;
      unsigned int bits = (((unsigned int)wds[kk]) >> (quad * 8)) & 0xffu;
      float4 q0 = *(const float4*)(sdst + j0);
      float4 q1 = *(const float4*)(sdst + j0 + 4);
      float sdv[8] = {q0.x, q0.y, q0.z, q0.w, q1.x, q1.y, q1.z, q1.w};
      float pe[8];
#pragma unroll
      for (int jj = 0; jj < 8; jj++) {
        float t = si + sdv[jj];
        float e = __expf(fmaxf(t, 0.2f * t));
        pe[jj] = ((bits >> jj) & 1u) ? e : 0.f;
        lsum += pe[jj];
      }
      i4s8 a;
      a.i.x = cvtpk(pe[0], pe[1]); a.i.y = cvtpk(pe[2], pe[3]);
      a.i.z = cvtpk(pe[4], pe[5]); a.i.w = cvtpk(pe[6], pe[7]);
      const short8* Bk = Bp + (size_t)kb * 256 + lane;
      short8 b0 = Bk[0], b1 = Bk[64], b2 = Bk[128], b3 = Bk[192];
      acc0 = __builtin_amdgcn_mfma_f32_16x16x32_bf16(a.s, b0, acc0, 0, 0, 0);
      acc1 = __builtin_amdgcn_mfma_f32_16x16x32_bf16(a.s, b1, acc1, 0, 0, 0);
      acc2 = __builtin_amdgcn_mfma_f32_16x16x32_bf16(a.s, b2, acc2, 0, 0, 0);
      acc3 = __builtin_amdgcn_mfma_f32_16x16x32_bf16(a.s, b3, acc3, 0, 0, 0);
    }
  }
  lsum += __shfl_xor(lsum, 16);
  lsum += __shfl_xor(lsum, 32);
  __shared__ float accs[8][16][66];
  __shared__ float ls2[8][16];
  if (w >= 8) {
    const int slot = w - 8;
    if (lane < 16) ls2[slot][lane] = lsum;
#pragma unroll
    for (int g = 0; g < 4; g++) {
      int r = quad * 4 + g;
      accs[slot][r][ 0 + r15] = acc0[g];
      accs[slot][r][16 + r15] = acc1[g];
      accs[slot][r][32 + r15] = acc2[g];
      accs[slot][r][48 + r15] = acc3[g];
    }
  }
  __syncthreads();
  if (w < 8) {
    const int slot = w;
    if (lane < 16) ls2[slot][lane] += lsum;
#pragma unroll
    for (int g = 0; g < 4; g++) {
      int r = quad * 4 + g;
      accs[slot][r][ 0 + r15] += acc0[g];
      accs[slot][r][16 + r15] += acc1[g];
      accs[slot][r][32 + r15] += acc2[g];
      accs[slot][r][48 + r15] += acc3[g];
    }
  }
  __syncthreads();
  {
    const int r = tid >> 6, col = tid & 63;
    float s = 0.f, lt = 0.f;
#pragma unroll
    for (int k = 0; k < 8; k++) { s += accs[k][r][col]; lt += ls2[k][r]; }
    float v = (lt > 0.f) ? s / lt : 0.f;
    v = v > 0.f ? v : __expf(v) - 1.f;
    size_t idx = (size_t)(rb * 16 + r) * 64 + col;
    if (flags[0]) ((unsigned short*)outv)[idx] = f2bf(v);
    else          ((float*)outv)[idx] = v;
  }
}

extern "C" void kernel_launch(void* const* d_in, const int* in_sizes, int n_in,
                              void* d_out, int out_size, void* d_ws, size_t ws_size,
                              hipStream_t stream) {
  const void* h      = d_in[0];
  const void* adj    = d_in[1];
  const void* Wh     = d_in[2];
  const void* bWh    = d_in[3];
  const void* a_src  = d_in[4];
  const void* a_dst  = d_in[5];
  const void* a_b    = d_in[6];
  const void* Wo     = d_in[7];
  const void* bWo    = d_in[8];
  const void* ao_src = d_in[9];
  const void* ao_dst = d_in[10];
  const void* ao_b   = d_in[11];

  size_t need_old = 16 + (size_t)NN * 512 + (size_t)NHEADS * NN * HID * 2 +
                    (size_t)NN * 256 * 2 + (size_t)NN * 64 * 2 +
                    (size_t)NHEADS * NN * 8 + (size_t)NN * 8;
  size_t need_new = need_old + (size_t)2 * NN * 256 * 4 + (size_t)2 * 4 * NN * 4;
  hipMemsetAsync(d_out, 0x41, (size_t)out_size * 2, stream);
  if (ws_size < need_old) {
    hipMemsetAsync(d_out, 0x45, (size_t)out_size * 2, stream);
    return;
  }
  const bool big = ws_size >= need_new;
  unsigned char* ws = (unsigned char*)d_ws;
  int* flags = (int*)ws;                        ws += 16;
  unsigned char* bmp = ws;                      ws += (size_t)NN * 512;               // 2 MB
  unsigned short* Bp1 = (unsigned short*)ws;    ws += (size_t)NHEADS * NN * HID * 2;  // 2 MB
  unsigned short* x2  = (unsigned short*)ws;    ws += (size_t)NN * 256 * 2;           // 2 MB
  unsigned short* Bp2 = (unsigned short*)ws;    ws += (size_t)NN * 64 * 2;            // 512 KB
  float* ssrc1 = (float*)ws;                    ws += (size_t)NHEADS * NN * 4;
  float* sdst1 = (float*)ws;                    ws += (size_t)NHEADS * NN * 4;
  float* ssrc2 = (float*)ws;                    ws += (size_t)NN * 4;
  float* sdst2 = (float*)ws;                    ws += (size_t)NN * 4;
  float* part  = (float*)ws;                    ws += (size_t)2 * NN * 256 * 4;       // 8 MB
  float* partl = (float*)ws;                    ws += (size_t)2 * 4 * NN * 4;         // 128 KB

  k_probe<<<dim3(1),    dim3(256),  0, stream>>>(h, adj, flags);
  k_bm   <<<dim3(4096), dim3(256),  0, stream>>>(adj, flags, bmp);
  k_wh   <<<dim3(1024), dim3(256),  0, stream>>>(h, Wh, bWh, a_src, a_dst, a_b, flags,
                                                 Bp1, ssrc1, sdst1);
  if (big) {
    k_att1s<<<dim3(256),  dim3(1024), 0, stream>>>(bmp, ssrc1, sdst1, (const short8*)Bp1,
                                                   part, partl);
    k_att1f<<<dim3(1024), dim3(256),  0, stream>>>(part, partl, x2);
  } else {
    k_att1<<<dim3(256), dim3(1024), 0, stream>>>(bmp, ssrc1, sdst1, (const short8*)Bp1, x2);
  }
  k_wo   <<<dim3(1024), dim3(256),  0, stream>>>(x2, Wo, bWo, ao_src, ao_dst, ao_b, flags,
                                                 Bp2, ssrc2, sdst2);
  k_att2 <<<dim3(256),  dim3(1024), 0, stream>>>(bmp, ssrc2, sdst2, (const short8*)Bp2,
                                                 flags, d_out);
}

// Round 6
// 207.949 us; speedup vs baseline: 1.0538x; 1.0538x over previous
//
#include <hip/hip_runtime.h>

#define NN 4096
#define NHEADS 4
#define HID 64
#define INDIM 256

using short8 = __attribute__((ext_vector_type(8))) short;
using f32x4  = __attribute__((ext_vector_type(4))) float;

union f32u { float f; unsigned int u; };
union i4s8 { int4 i; short8 s; };

__device__ __forceinline__ float bf2f(unsigned short s) {
  f32u x; x.u = ((unsigned int)s) << 16; return x.f;
}
__device__ __forceinline__ unsigned short f2bf(float f) {
  f32u x; x.f = f;
  unsigned int r = x.u + 0x7fffu + ((x.u >> 16) & 1u);
  return (unsigned short)(r >> 16);
}
// packed f32x2 -> bf16x2 (RNE, same as f2bf) in one instruction
__device__ __forceinline__ unsigned int cvtpk(float lo, float hi) {
  unsigned int r;
  asm("v_cvt_pk_bf16_f32 %0, %1, %2" : "=v"(r) : "v"(lo), "v"(hi));
  return r;
}

// overloaded external-input loaders
__device__ __forceinline__ float ld(const unsigned short* p, size_t i) { return bf2f(p[i]); }
__device__ __forceinline__ float ld(const float* p, size_t i) { return p[i]; }
// vectorized 8-element loader (16B for bf16, 2x16B for fp32) — p must be 8-elem aligned
__device__ __forceinline__ void ld8(const unsigned short* p, float* out) {
  short8 v = *(const short8*)p;
#pragma unroll
  for (int j = 0; j < 8; j++) out[j] = bf2f((unsigned short)v[j]);
}
__device__ __forceinline__ void ld8(const float* p, float* out) {
  float4 a = *(const float4*)p;
  float4 b = *(const float4*)(p + 4);
  out[0] = a.x; out[1] = a.y; out[2] = a.z; out[3] = a.w;
  out[4] = b.x; out[5] = b.y; out[6] = b.z; out[7] = b.w;
}

// ---------------- Probe: classify input dtypes at runtime (parallel, 256 threads).
__global__ __launch_bounds__(256) void k_probe(const void* hv, const void* adjv, int* flags) {
  __shared__ int s_bad, s_at;
  const int tid = threadIdx.x;
  if (tid == 0) { s_bad = 0; s_at = 0; }
  __syncthreads();
  const unsigned short* hu = (const unsigned short*)hv;
  float v = bf2f(hu[tid]);
  if (!(v > -1000.f && v < 1000.f)) atomicOr(&s_bad, 1);
  const unsigned int* au = (const unsigned int*)adjv;
  unsigned int wv = au[tid];
  if ((wv & 0xFFFFu) == 0x3F80u) atomicOr(&s_at, 2);
  else if (wv == 0x3F800000u) atomicOr(&s_at, 1);
  __syncthreads();
  if (tid == 0) {
    flags[0] = s_bad ? 0 : 1;
    int at = s_at;
    flags[1] = (at & 2) ? 2 : (at & 1);
  }
}

// ---------------- K0: adj -> bitmask bytes bm[i][j>>3]
__global__ __launch_bounds__(256) void k_bm(const void* adjv, const int* __restrict__ flags,
                                            unsigned char* __restrict__ bm) {
  const int at = flags[1];
  const int i = blockIdx.x;
#pragma unroll
  for (int rep = 0; rep < 2; rep++) {
    int jb = threadIdx.x + rep * 256;
    unsigned int b = 0;
    if (at == 0) {
      const int4* arow = (const int4*)((const int*)adjv + (size_t)i * NN);
      int4 a0 = arow[jb * 2 + 0];
      int4 a1 = arow[jb * 2 + 1];
      b |= (a0.x > 0) ? 1u : 0u;  b |= (a0.y > 0) ? 2u : 0u;
      b |= (a0.z > 0) ? 4u : 0u;  b |= (a0.w > 0) ? 8u : 0u;
      b |= (a1.x > 0) ? 16u : 0u; b |= (a1.y > 0) ? 32u : 0u;
      b |= (a1.z > 0) ? 64u : 0u; b |= (a1.w > 0) ? 128u : 0u;
    } else if (at == 1) {
      const float* arow = (const float*)adjv + (size_t)i * NN + jb * 8;
      for (int t = 0; t < 8; t++) b |= (arow[t] > 0.5f) ? (1u << t) : 0u;
    } else {
      const unsigned short* arow = (const unsigned short*)adjv + (size_t)i * NN + jb * 8;
      for (int t = 0; t < 8; t++) b |= (bf2f(arow[t]) > 0.5f) ? (1u << t) : 0u;
    }
    bm[(size_t)i * 512 + jb] = (unsigned char)b;
  }
}

// ---------------- K1: wh = h@Wh + bWh. v3: 16-row tile/block, 1024 thr = 16 waves =
// 4 heads x 4 k-quarters. 16 indep acc chains/thread (ILP), W amortized 16x, two-slot
// LDS combine (k_att1s pattern), pack phase writes full int4 Bp1 units + LDS dots.
template <typename T>
__device__ __forceinline__ void wh_body(const T* h, const T* Wh, const T* bWh,
    const T* a_src, const T* a_dst, const T* a_b,
    unsigned short* __restrict__ Bp1, float* __restrict__ ssrc1, float* __restrict__ sdst1,
    float (*wp)[16][260], float* av0, float* av1) {
  const int tid = threadIdx.x;
  const int w = tid >> 6, lane = tid & 63;
  const int head = w & 3, kq = w >> 2;
  const int rb = blockIdx.x;       // 0..255, 16 rows each
  const int R0 = rb * 16;
  const int d = lane;
  // stage attention vectors (4 heads x 64)
  if (tid < 256) av0[tid] = ld(a_src, tid);
  else if (tid < 512) av1[tid - 256] = ld(a_dst, tid - 256);
  // partial GEMM: this wave covers k in [kq*64, kq*64+64)
  float acc[16];
  float bv = (kq == 0) ? ld(bWh, head * 64 + d) : 0.f;
#pragma unroll
  for (int r = 0; r < 16; r++) acc[r] = bv;
  const int k0 = kq * 64;
  for (int kb = 0; kb < 8; kb++) {
    float wv[8];
#pragma unroll
    for (int j = 0; j < 8; j++)
      wv[j] = ld(Wh, (size_t)(head * 256 + k0 + kb * 8 + j) * 64 + d);
#pragma unroll
    for (int r = 0; r < 16; r++) {
      float hf[8];
      ld8(h + (size_t)(R0 + r) * 256 + k0 + kb * 8, hf);
#pragma unroll
      for (int j = 0; j < 8; j++) acc[r] = fmaf(hf[j], wv[j], acc[r]);
    }
  }
  // two-slot combine: kq {2,3} write slots {0,1}; kq {0,1} add; pack sums both slots.
  if (kq >= 2) {
#pragma unroll
    for (int r = 0; r < 16; r++) wp[kq - 2][r][head * 64 + d] = acc[r];
  }
  __syncthreads();
  if (kq < 2) {
#pragma unroll
    for (int r = 0; r < 16; r++) wp[kq][r][head * 64 + d] += acc[r];
  }
  __syncthreads();
  // pack phase (parallel): tids 0-511 write Bp1 int4 units; 512-575 compute dots.
  if (tid < 512) {
    const int hh = tid >> 7, tt = (tid >> 5) & 3, lnh = tid & 31;
    const int q2 = (rb & 1) * 2 + (lnh >> 4);
    const int ln = q2 * 16 + (lnh & 15);
    const int dd = tt * 16 + (lnh & 15);
    const int rbase = (lnh >> 4) * 8;
    float v[8];
#pragma unroll
    for (int jj = 0; jj < 8; jj++)
      v[jj] = wp[0][rbase + jj][hh * 64 + dd] + wp[1][rbase + jj][hh * 64 + dd];
    i4s8 s;
    s.i.x = cvtpk(v[0], v[1]); s.i.y = cvtpk(v[2], v[3]);
    s.i.z = cvtpk(v[4], v[5]); s.i.w = cvtpk(v[6], v[7]);
    const int kb = rb >> 1;
    *(int4*)(Bp1 + ((((size_t)hh * 128 + kb) * 4 + tt) * 64 + ln) * 8) = s.i;
  } else if (tid < 576) {
    const int t2 = tid - 512;
    const int hh = t2 >> 4, r = t2 & 15;
    float ps = 0.f, pd = 0.f;
    for (int c = 0; c < 64; c++) {
      float wv2 = wp[0][r][hh * 64 + c] + wp[1][r][hh * 64 + c];
      ps = fmaf(wv2, av0[hh * 64 + c], ps);
      pd = fmaf(wv2, av1[hh * 64 + c], pd);
    }
    ssrc1[hh * NN + R0 + r] = ps + ld(a_b, hh);
    sdst1[hh * NN + R0 + r] = pd;
  }
}
__global__ __launch_bounds__(1024, 4) void k_wh(const void* h, const void* Wh, const void* bWh,
    const void* a_src, const void* a_dst, const void* a_b, const int* __restrict__ flags,
    unsigned short* Bp1, float* ssrc1, float* sdst1) {
  __shared__ float wp[2][16][260];
  __shared__ float av0[256], av1[256];
  if (flags[0])
    wh_body<unsigned short>((const unsigned short*)h, (const unsigned short*)Wh,
        (const unsigned short*)bWh, (const unsigned short*)a_src,
        (const unsigned short*)a_dst, (const unsigned short*)a_b, Bp1, ssrc1, sdst1,
        wp, av0, av1);
  else
    wh_body<float>((const float*)h, (const float*)Wh, (const float*)bWh, (const float*)a_src,
        (const float*)a_dst, (const float*)a_b, Bp1, ssrc1, sdst1, wp, av0, av1);
}

// ---------------- K2-new: layer-1 attention. Grid 256 = 128 rowblocks(32 rows) x 2 kb-halves.
// 1024 thr = 16 waves = 4 heads x 4 slices(16 kb). Two A-frags/wave share every B load.
__global__ __launch_bounds__(1024, 4) void k_att1s(
    const unsigned char* __restrict__ bm, const float* __restrict__ ssrc,
    const float* __restrict__ sdst, const short8* __restrict__ Bp,
    float* __restrict__ part, float* __restrict__ partl) {
  const int rb = blockIdx.x & 127;
  const int half = blockIdx.x >> 7;
  const int tid = threadIdx.x;
  const int w = tid >> 6;
  const int head = w & 3;
  const int sl = w >> 2;  // 0..3: 16-kb slice within this half
  const int lane = tid & 63;
  const int r15 = lane & 15, quad = lane >> 4;
  const int row0 = rb * 32 + r15;
  const int row1 = row0 + 16;
  const float si0 = ssrc[head * NN + row0];
  const float si1 = ssrc[head * NN + row1];
  const unsigned char* bmr0 = bm + (size_t)row0 * 512;
  const unsigned char* bmr1 = bm + (size_t)row1 * 512;
  const float* sd = sdst + head * NN;
  const short8* Bh = Bp + (size_t)head * 128 * 4 * 64;
  f32x4 acc0[4], acc1[4];
#pragma unroll
  for (int t = 0; t < 4; t++) { acc0[t] = (f32x4){0,0,0,0}; acc1[t] = (f32x4){0,0,0,0}; }
  float ls0 = 0.f, ls1 = 0.f;
  const int kb0 = half * 64 + sl * 16;
  for (int g = 0; g < 4; g++) {          // 4 kb per group, bm fetched as int4
    const int kbg = kb0 + g * 4;
    int4 u0 = *(const int4*)(bmr0 + kbg * 4);
    int4 u1 = *(const int4*)(bmr1 + kbg * 4);
    int wd0[4] = {u0.x, u0.y, u0.z, u0.w};
    int wd1[4] = {u1.x, u1.y, u1.z, u1.w};
#pragma unroll
    for (int kk = 0; kk < 4; kk++) {
      const int kb = kbg + kk;
      const int j0 = kb * 32 + quad * 8;
      float4 q0 = *(const float4*)(sd + j0);
      float4 q1 = *(const float4*)(sd + j0 + 4);
      float sdv[8] = {q0.x, q0.y, q0.z, q0.w, q1.x, q1.y, q1.z, q1.w};
      unsigned int bits0 = (((unsigned int)wd0[kk]) >> (quad * 8)) & 0xffu;
      unsigned int bits1 = (((unsigned int)wd1[kk]) >> (quad * 8)) & 0xffu;
      float pe0[8], pe1[8];
#pragma unroll
      for (int jj = 0; jj < 8; jj++) {
        float t0 = si0 + sdv[jj];
        float e0 = __expf(fmaxf(t0, 0.2f * t0));
        pe0[jj] = ((bits0 >> jj) & 1u) ? e0 : 0.f;
        ls0 += pe0[jj];
        float t1 = si1 + sdv[jj];
        float e1 = __expf(fmaxf(t1, 0.2f * t1));
        pe1[jj] = ((bits1 >> jj) & 1u) ? e1 : 0.f;
        ls1 += pe1[jj];
      }
      i4s8 a0, a1;
      a0.i.x = cvtpk(pe0[0], pe0[1]); a0.i.y = cvtpk(pe0[2], pe0[3]);
      a0.i.z = cvtpk(pe0[4], pe0[5]); a0.i.w = cvtpk(pe0[6], pe0[7]);
      a1.i.x = cvtpk(pe1[0], pe1[1]); a1.i.y = cvtpk(pe1[2], pe1[3]);
      a1.i.z = cvtpk(pe1[4], pe1[5]); a1.i.w = cvtpk(pe1[6], pe1[7]);
      const short8* Bk = Bh + (size_t)kb * 256 + lane;
      short8 bt[4];
      bt[0] = Bk[0]; bt[1] = Bk[64]; bt[2] = Bk[128]; bt[3] = Bk[192];
#pragma unroll
      for (int t = 0; t < 4; t++) {
        acc0[t] = __builtin_amdgcn_mfma_f32_16x16x32_bf16(a0.s, bt[t], acc0[t], 0, 0, 0);
        acc1[t] = __builtin_amdgcn_mfma_f32_16x16x32_bf16(a1.s, bt[t], acc1[t], 0, 0, 0);
      }
    }
  }
  ls0 += __shfl_xor(ls0, 16); ls0 += __shfl_xor(ls0, 32);
  ls1 += __shfl_xor(ls1, 16); ls1 += __shfl_xor(ls1, 32);
  // combine 4 slices via 8 slots (head x 2): slices {2,3} write, {0,1} add; out sums pair.
  __shared__ float accs[8][16][66];
  __shared__ float lsh[8][16];
#define DOPASS(AC, LSV, PASS)                                                  \
  do {                                                                         \
    if (sl >= 2) {                                                             \
      const int slot = head * 2 + (sl - 2);                                    \
      if (lane < 16) lsh[slot][lane] = (LSV);                                  \
      _Pragma("unroll") for (int t = 0; t < 4; t++)                            \
        _Pragma("unroll") for (int gg = 0; gg < 4; gg++)                       \
          accs[slot][quad * 4 + gg][t * 16 + r15] = (AC)[t][gg];               \
    }                                                                          \
    __syncthreads();                                                           \
    if (sl < 2) {                                                              \
      const int slot = head * 2 + sl;                                          \
      if (lane < 16) lsh[slot][lane] += (LSV);                                 \
      _Pragma("unroll") for (int t = 0; t < 4; t++)                            \
        _Pragma("unroll") for (int gg = 0; gg < 4; gg++)                       \
          accs[slot][quad * 4 + gg][t * 16 + r15] += (AC)[t][gg];              \
    }                                                                          \
    __syncthreads();                                                           \
    _Pragma("unroll") for (int idx = tid; idx < 4096; idx += 1024) {           \
      int r = idx >> 8, hc = idx & 255;                                        \
      int hh = hc >> 6, col = hc & 63;                                         \
      part[((size_t)half * NN + rb * 32 + (PASS) * 16 + r) * 256 + hc] =       \
          accs[hh * 2][r][col] + accs[hh * 2 + 1][r][col];                     \
    }                                                                          \
    if (tid < 64)                                                              \
      partl[((size_t)half * 4 + (tid >> 4)) * NN + rb * 32 + (PASS) * 16 +     \
            (tid & 15)] = lsh[(tid >> 4) * 2][tid & 15] +                      \
                          lsh[(tid >> 4) * 2 + 1][tid & 15];                   \
    __syncthreads();                                                           \
  } while (0)
  DOPASS(acc0, ls0, 0);
  DOPASS(acc1, ls1, 1);
#undef DOPASS
}

// ---------------- K2-fin: sum the 2 kb-half partials, normalize, elu, pack bf16.
__global__ __launch_bounds__(256) void k_att1f(const float* __restrict__ part,
    const float* __restrict__ partl, unsigned short* __restrict__ x2) {
  const int idx = blockIdx.x * 256 + threadIdx.x;  // 262144 = 4096 rows x 64 col-quads
  const int row = idx >> 6;
  const int c4 = (idx & 63) * 4;
  const int head = c4 >> 6;
  const size_t off = (size_t)row * 256 + c4;
  float4 p0 = *(const float4*)(part + off);
  float4 p1 = *(const float4*)(part + (size_t)NN * 256 + off);
  float lt = partl[(size_t)head * NN + row] + partl[(size_t)(4 + head) * NN + row];
  float rl = (lt > 0.f) ? 1.f / lt : 0.f;
  float v0 = (p0.x + p1.x) * rl, v1 = (p0.y + p1.y) * rl;
  float v2 = (p0.z + p1.z) * rl, v3 = (p0.w + p1.w) * rl;
  v0 = v0 > 0.f ? v0 : __expf(v0) - 1.f;
  v1 = v1 > 0.f ? v1 : __expf(v1) - 1.f;
  v2 = v2 > 0.f ? v2 : __expf(v2) - 1.f;
  v3 = v3 > 0.f ? v3 : __expf(v3) - 1.f;
  uint2 st; st.x = cvtpk(v0, v1); st.y = cvtpk(v2, v3);
  *(uint2*)(x2 + off) = st;
}

// ---------------- K2-old (fallback if workspace too small for partials)
__global__ __launch_bounds__(1024) void k_att1(
    const unsigned char* __restrict__ bm, const float* __restrict__ ssrc,
    const float* __restrict__ sdst, const short8* __restrict__ Bp,
    unsigned short* __restrict__ x2) {
  const int rb = blockIdx.x;
  const int tid = threadIdx.x;
  const int w = tid >> 6;
  const int head = w & 3;
  const int slice = w >> 2;
  const int lane = tid & 63;
  const int r15 = lane & 15, quad = lane >> 4;
  const int row = rb * 16 + r15;
  const float si = ssrc[head * NN + row];
  const unsigned char* bmrow = bm + (size_t)row * 512;
  const float* sd = sdst + head * NN;
  const short8* Bh = Bp + (size_t)head * 128 * 4 * 64;
  f32x4 acc0 = {0, 0, 0, 0}, acc1 = {0, 0, 0, 0}, acc2 = {0, 0, 0, 0}, acc3 = {0, 0, 0, 0};
  float lsum = 0.f;
  const int kb0 = slice * 32;
  for (int kb = kb0; kb < kb0 + 32; kb++) {
    const int j0 = kb * 32 + quad * 8;
    unsigned int bits = bmrow[kb * 4 + quad];
    float4 q0 = *(const float4*)(sd + j0);
    float4 q1 = *(const float4*)(sd + j0 + 4);
    float sdv[8] = {q0.x, q0.y, q0.z, q0.w, q1.x, q1.y, q1.z, q1.w};
    short8 af;
#pragma unroll
    for (int jj = 0; jj < 8; jj++) {
      float t = si + sdv[jj];
      float lr = fmaxf(t, 0.2f * t);
      float e = __expf(lr);
      float pe = ((bits >> jj) & 1u) ? e : 0.0f;
      lsum += pe;
      af[jj] = (short)f2bf(pe);
    }
    const short8* Bk = Bh + (size_t)kb * 256 + lane;
    short8 b0 = Bk[0], b1 = Bk[64], b2 = Bk[128], b3 = Bk[192];
    acc0 = __builtin_amdgcn_mfma_f32_16x16x32_bf16(af, b0, acc0, 0, 0, 0);
    acc1 = __builtin_amdgcn_mfma_f32_16x16x32_bf16(af, b1, acc1, 0, 0, 0);
    acc2 = __builtin_amdgcn_mfma_f32_16x16x32_bf16(af, b2, acc2, 0, 0, 0);
    acc3 = __builtin_amdgcn_mfma_f32_16x16x32_bf16(af, b3, acc3, 0, 0, 0);
  }
  lsum += __shfl_xor(lsum, 16);
  lsum += __shfl_xor(lsum, 32);
  __shared__ float accs[8][16][66];
  __shared__ float ls[8][16];
  if (slice >= 2) {
    const int slot = w - 8;
    if (lane < 16) ls[slot][lane] = lsum;
#pragma unroll
    for (int g = 0; g < 4; g++) {
      int r = quad * 4 + g;
      accs[slot][r][ 0 + r15] = acc0[g];
      accs[slot][r][16 + r15] = acc1[g];
      accs[slot][r][32 + r15] = acc2[g];
      accs[slot][r][48 + r15] = acc3[g];
    }
  }
  __syncthreads();
  if (slice < 2) {
    const int slot = w;
    if (lane < 16) ls[slot][lane] += lsum;
#pragma unroll
    for (int g = 0; g < 4; g++) {
      int r = quad * 4 + g;
      accs[slot][r][ 0 + r15] += acc0[g];
      accs[slot][r][16 + r15] += acc1[g];
      accs[slot][r][32 + r15] += acc2[g];
      accs[slot][r][48 + r15] += acc3[g];
    }
  }
  __syncthreads();
#pragma unroll
  for (int c = tid; c < 4096; c += 1024) {
    int r = c >> 8, hc = c & 255;
    int hh = hc >> 6, col = hc & 63;
    float s = accs[hh][r][col] + accs[hh + 4][r][col];
    float lt = ls[hh][r] + ls[hh + 4][r];
    float v = (lt > 0.f) ? s / lt : 0.f;
    v = v > 0.f ? v : __expf(v) - 1.f;
    x2[(size_t)(rb * 16 + r) * 256 + hc] = f2bf(v);
  }
}

// ---------------- K3: wo = x2@Wo + bWo. v2: 16-row tile/block, 1024 thr = 16 waves =
// 4 row-groups x 4 k-quarters; two-slot LDS combine + pack (same pattern as k_wh).
template <typename T>
__device__ __forceinline__ void wo_body(const unsigned short* x2, const T* Wo, const T* bWo,
    const T* ao_src, const T* ao_dst, const T* ao_b,
    unsigned short* __restrict__ Bp2, float* __restrict__ ssrc2, float* __restrict__ sdst2,
    float (*wp)[16][68], float* av) {
  const int tid = threadIdx.x;
  const int w = tid >> 6, lane = tid & 63;
  const int rg = w & 3, kq = w >> 2;
  const int rb = blockIdx.x;         // 0..255, 16 rows each
  const int R0 = rb * 16 + rg * 4;   // this wave's 4 rows
  const int d = lane;
  if (tid < 64) av[tid] = ld(ao_src, tid);
  else if (tid < 128) av[tid] = ld(ao_dst, tid - 64);
  float acc[4];
  float bv = (kq == 0) ? ld(bWo, d) : 0.f;
#pragma unroll
  for (int r = 0; r < 4; r++) acc[r] = bv;
  const int k0 = kq * 64;
  for (int kb = 0; kb < 8; kb++) {
    float wv[8];
#pragma unroll
    for (int j = 0; j < 8; j++)
      wv[j] = ld(Wo, (size_t)(k0 + kb * 8 + j) * 64 + d);
#pragma unroll
    for (int r = 0; r < 4; r++) {
      float hf[8];
      ld8(x2 + (size_t)(R0 + r) * 256 + k0 + kb * 8, hf);
#pragma unroll
      for (int j = 0; j < 8; j++) acc[r] = fmaf(hf[j], wv[j], acc[r]);
    }
  }
  const int rr = rg * 4;
  if (kq >= 2) {
#pragma unroll
    for (int r = 0; r < 4; r++) wp[kq - 2][rr + r][d] = acc[r];
  }
  __syncthreads();
  if (kq < 2) {
#pragma unroll
    for (int r = 0; r < 4; r++) wp[kq][rr + r][d] += acc[r];
  }
  __syncthreads();
  if (tid < 128) {
    const int tt = tid >> 5, lnh = tid & 31;
    const int q2 = (rb & 1) * 2 + (lnh >> 4);
    const int ln = q2 * 16 + (lnh & 15);
    const int dd = tt * 16 + (lnh & 15);
    const int rbase = (lnh >> 4) * 8;
    float v[8];
#pragma unroll
    for (int jj = 0; jj < 8; jj++)
      v[jj] = wp[0][rbase + jj][dd] + wp[1][rbase + jj][dd];
    i4s8 s;
    s.i.x = cvtpk(v[0], v[1]); s.i.y = cvtpk(v[2], v[3]);
    s.i.z = cvtpk(v[4], v[5]); s.i.w = cvtpk(v[6], v[7]);
    const int kb = rb >> 1;
    *(int4*)(Bp2 + (((size_t)kb * 4 + tt) * 64 + ln) * 8) = s.i;
  } else if (tid < 144) {
    const int r = tid - 128;
    float ps = 0.f, pd = 0.f;
    for (int c = 0; c < 64; c++) {
      float wv2 = wp[0][r][c] + wp[1][r][c];
      ps = fmaf(wv2, av[c], ps);
      pd = fmaf(wv2, av[64 + c], pd);
    }
    ssrc2[(size_t)rb * 16 + r] = ps + ld(ao_b, 0);
    sdst2[(size_t)rb * 16 + r] = pd;
  }
}
__global__ __launch_bounds__(1024, 4) void k_wo(const unsigned short* __restrict__ x2,
    const void* Wo, const void* bWo, const void* ao_src, const void* ao_dst, const void* ao_b,
    const int* __restrict__ flags, unsigned short* Bp2, float* ssrc2, float* sdst2) {
  __shared__ float wp[2][16][68];
  __shared__ float av[128];
  if (flags[0])
    wo_body<unsigned short>(x2, (const unsigned short*)Wo, (const unsigned short*)bWo,
        (const unsigned short*)ao_src, (const unsigned short*)ao_dst,
        (const unsigned short*)ao_b, Bp2, ssrc2, sdst2, wp, av);
  else
    wo_body<float>(x2, (const float*)Wo, (const float*)bWo, (const float*)ao_src,
        (const float*)ao_dst, (const float*)ao_b, Bp2, ssrc2, sdst2, wp, av);
}

// ---------------- K4: layer-2 attention (1 head), 16 rows/block, 16-way j-split.
__global__ __launch_bounds__(1024) void k_att2(
    const unsigned char* __restrict__ bm, const float* __restrict__ ssrc,
    const float* __restrict__ sdst, const short8* __restrict__ Bp,
    const int* __restrict__ flags, void* __restrict__ outv) {
  const int rb = blockIdx.x;
  const int tid = threadIdx.x;
  const int w = tid >> 6;  // j-slice 0..15
  const int lane = tid & 63;
  const int r15 = lane & 15, quad = lane >> 4;
  const int row = rb * 16 + r15;
  const float si = ssrc[row];
  const unsigned char* bmrow = bm + (size_t)row * 512;
  f32x4 acc0 = {0, 0, 0, 0}, acc1 = {0, 0, 0, 0}, acc2 = {0, 0, 0, 0}, acc3 = {0, 0, 0, 0};
  float lsum = 0.f;
  const int kb0 = w * 8;
#pragma unroll
  for (int g = 0; g < 2; g++) {
    int4 ubm = *(const int4*)(bmrow + (kb0 + g * 4) * 4);
    int wds[4] = {ubm.x, ubm.y, ubm.z, ubm.w};
#pragma unroll
    for (int kk = 0; kk < 4; kk++) {
      const int kb = kb0 + g * 4 + kk;
      const int j0 = kb * 32 + quad * 8;
      unsigned int bits = (((unsigned int)wds[kk]) >> (quad * 8)) & 0xffu;
      float4 q0 = *(const float4*)(sdst + j0);
      float4 q1 = *(const float4*)(sdst + j0 + 4);
      float sdv[8] = {q0.x, q0.y, q0.z, q0.w, q1.x, q1.y, q1.z, q1.w};
      float pe[8];
#pragma unroll
      for (int jj = 0; jj < 8; jj++) {
        float t = si + sdv[jj];
        float e = __expf(fmaxf(t, 0.2f * t));
        pe[jj] = ((bits >> jj) & 1u) ? e : 0.f;
        lsum += pe[jj];
      }
      i4s8 a;
      a.i.x = cvtpk(pe[0], pe[1]); a.i.y = cvtpk(pe[2], pe[3]);
      a.i.z = cvtpk(pe[4], pe[5]); a.i.w = cvtpk(pe[6], pe[7]);
      const short8* Bk = Bp + (size_t)kb * 256 + lane;
      short8 b0 = Bk[0], b1 = Bk[64], b2 = Bk[128], b3 = Bk[192];
      acc0 = __builtin_amdgcn_mfma_f32_16x16x32_bf16(a.s, b0, acc0, 0, 0, 0);
      acc1 = __builtin_amdgcn_mfma_f32_16x16x32_bf16(a.s, b1, acc1, 0, 0, 0);
      acc2 = __builtin_amdgcn_mfma_f32_16x16x32_bf16(a.s, b2, acc2, 0, 0, 0);
      acc3 = __builtin_amdgcn_mfma_f32_16x16x32_bf16(a.s, b3, acc3, 0, 0, 0);
    }
  }
  lsum += __shfl_xor(lsum, 16);
  lsum += __shfl_xor(lsum, 32);
  __shared__ float accs[8][16][66];
  __shared__ float ls2[8][16];
  if (w >= 8) {
    const int slot = w - 8;
    if (lane < 16) ls2[slot][lane] = lsum;
#pragma unroll
    for (int g = 0; g < 4; g++) {
      int r = quad * 4 + g;
      accs[slot][r][ 0 + r15] = acc0[g];
      accs[slot][r][16 + r15] = acc1[g];
      accs[slot][r][32 + r15] = acc2[g];
      accs[slot][r][48 + r15] = acc3[g];
    }
  }
  __syncthreads();
  if (w < 8) {
    const int slot = w;
    if (lane < 16) ls2[slot][lane] += lsum;
#pragma unroll
    for (int g = 0; g < 4; g++) {
      int r = quad * 4 + g;
      accs[slot][r][ 0 + r15] += acc0[g];
      accs[slot][r][16 + r15] += acc1[g];
      accs[slot][r][32 + r15] += acc2[g];
      accs[slot][r][48 + r15] += acc3[g];
    }
  }
  __syncthreads();
  {
    const int r = tid >> 6, col = tid & 63;
    float s = 0.f, lt = 0.f;
#pragma unroll
    for (int k = 0; k < 8; k++) { s += accs[k][r][col]; lt += ls2[k][r]; }
    float v = (lt > 0.f) ? s / lt : 0.f;
    v = v > 0.f ? v : __expf(v) - 1.f;
    size_t idx = (size_t)(rb * 16 + r) * 64 + col;
    if (flags[0]) ((unsigned short*)outv)[idx] = f2bf(v);
    else          ((float*)outv)[idx] = v;
  }
}

extern "C" void kernel_launch(void* const* d_in, const int* in_sizes, int n_in,
                              void* d_out, int out_size, void* d_ws, size_t ws_size,
                              hipStream_t stream) {
  const void* h      = d_in[0];
  const void* adj    = d_in[1];
  const void* Wh     = d_in[2];
  const void* bWh    = d_in[3];
  const void* a_src  = d_in[4];
  const void* a_dst  = d_in[5];
  const void* a_b    = d_in[6];
  const void* Wo     = d_in[7];
  const void* bWo    = d_in[8];
  const void* ao_src = d_in[9];
  const void* ao_dst = d_in[10];
  const void* ao_b   = d_in[11];

  size_t need_old = 16 + (size_t)NN * 512 + (size_t)NHEADS * NN * HID * 2 +
                    (size_t)NN * 256 * 2 + (size_t)NN * 64 * 2 +
                    (size_t)NHEADS * NN * 8 + (size_t)NN * 8;
  size_t need_new = need_old + (size_t)2 * NN * 256 * 4 + (size_t)2 * 4 * NN * 4;
  hipMemsetAsync(d_out, 0x41, (size_t)out_size * 2, stream);
  if (ws_size < need_old) {
    hipMemsetAsync(d_out, 0x45, (size_t)out_size * 2, stream);
    return;
  }
  const bool big = ws_size >= need_new;
  unsigned char* ws = (unsigned char*)d_ws;
  int* flags = (int*)ws;                        ws += 16;
  unsigned char* bmp = ws;                      ws += (size_t)NN * 512;               // 2 MB
  unsigned short* Bp1 = (unsigned short*)ws;    ws += (size_t)NHEADS * NN * HID * 2;  // 2 MB
  unsigned short* x2  = (unsigned short*)ws;    ws += (size_t)NN * 256 * 2;           // 2 MB
  unsigned short* Bp2 = (unsigned short*)ws;    ws += (size_t)NN * 64 * 2;            // 512 KB
  float* ssrc1 = (float*)ws;                    ws += (size_t)NHEADS * NN * 4;
  float* sdst1 = (float*)ws;                    ws += (size_t)NHEADS * NN * 4;
  float* ssrc2 = (float*)ws;                    ws += (size_t)NN * 4;
  float* sdst2 = (float*)ws;                    ws += (size_t)NN * 4;
  float* part  = (float*)ws;                    ws += (size_t)2 * NN * 256 * 4;       // 8 MB
  float* partl = (float*)ws;                    ws += (size_t)2 * 4 * NN * 4;         // 128 KB

  k_probe<<<dim3(1),    dim3(256),  0, stream>>>(h, adj, flags);
  k_bm   <<<dim3(4096), dim3(256),  0, stream>>>(adj, flags, bmp);
  k_wh   <<<dim3(256),  dim3(1024), 0, stream>>>(h, Wh, bWh, a_src, a_dst, a_b, flags,
                                                 Bp1, ssrc1, sdst1);
  if (big) {
    k_att1s<<<dim3(256),  dim3(1024), 0, stream>>>(bmp, ssrc1, sdst1, (const short8*)Bp1,
                                                   part, partl);
    k_att1f<<<dim3(1024), dim3(256),  0, stream>>>(part, partl, x2);
  } else {
    k_att1<<<dim3(256), dim3(1024), 0, stream>>>(bmp, ssrc1, sdst1, (const short8*)Bp1, x2);
  }
  k_wo   <<<dim3(256),  dim3(1024), 0, stream>>>(x2, Wo, bWo, ao_src, ao_dst, ao_b, flags,
                                                 Bp2, ssrc2, sdst2);
  k_att2 <<<dim3(256),  dim3(1024), 0, stream>>>(bmp, ssrc2, sdst2, (const short8*)Bp2,
                                                 flags, d_out);
}

// Round 7
// 184.007 us; speedup vs baseline: 1.1910x; 1.1301x over previous
//
#include <hip/hip_runtime.h>

#define NN 4096
#define NHEADS 4
#define HID 64
#define INDIM 256

using short8 = __attribute__((ext_vector_type(8))) short;
using f32x4  = __attribute__((ext_vector_type(4))) float;

union f32u { float f; unsigned int u; };
union i4s8 { int4 i; short8 s; };

__device__ __forceinline__ float bf2f(unsigned short s) {
  f32u x; x.u = ((unsigned int)s) << 16; return x.f;
}
__device__ __forceinline__ unsigned short f2bf(float f) {
  f32u x; x.f = f;
  unsigned int r = x.u + 0x7fffu + ((x.u >> 16) & 1u);
  return (unsigned short)(r >> 16);
}
// packed f32x2 -> bf16x2 (RNE, same as f2bf) in one instruction
__device__ __forceinline__ unsigned int cvtpk(float lo, float hi) {
  unsigned int r;
  asm("v_cvt_pk_bf16_f32 %0, %1, %2" : "=v"(r) : "v"(lo), "v"(hi));
  return r;
}

// overloaded external-input loaders
__device__ __forceinline__ float ld(const unsigned short* p, size_t i) { return bf2f(p[i]); }
__device__ __forceinline__ float ld(const float* p, size_t i) { return p[i]; }
// 4-element loader (8B for bf16, 16B for fp32) — p must be 4-elem aligned
__device__ __forceinline__ void ld4(const unsigned short* p, float* out) {
  short4 v = *(const short4*)p;
  out[0] = bf2f((unsigned short)v.x); out[1] = bf2f((unsigned short)v.y);
  out[2] = bf2f((unsigned short)v.z); out[3] = bf2f((unsigned short)v.w);
}
__device__ __forceinline__ void ld4(const float* p, float* out) {
  float4 a = *(const float4*)p;
  out[0] = a.x; out[1] = a.y; out[2] = a.z; out[3] = a.w;
}

// ---------------- Probe: classify input dtypes at runtime (parallel, 256 threads).
__global__ __launch_bounds__(256) void k_probe(const void* hv, const void* adjv, int* flags) {
  __shared__ int s_bad, s_at;
  const int tid = threadIdx.x;
  if (tid == 0) { s_bad = 0; s_at = 0; }
  __syncthreads();
  const unsigned short* hu = (const unsigned short*)hv;
  float v = bf2f(hu[tid]);
  if (!(v > -1000.f && v < 1000.f)) atomicOr(&s_bad, 1);
  const unsigned int* au = (const unsigned int*)adjv;
  unsigned int wv = au[tid];
  if ((wv & 0xFFFFu) == 0x3F80u) atomicOr(&s_at, 2);
  else if (wv == 0x3F800000u) atomicOr(&s_at, 1);
  __syncthreads();
  if (tid == 0) {
    flags[0] = s_bad ? 0 : 1;
    int at = s_at;
    flags[1] = (at & 2) ? 2 : (at & 1);
  }
}

// ---------------- K0: adj -> bitmask bytes bm[i][j>>3]
__global__ __launch_bounds__(256) void k_bm(const void* adjv, const int* __restrict__ flags,
                                            unsigned char* __restrict__ bm) {
  const int at = flags[1];
  const int i = blockIdx.x;
#pragma unroll
  for (int rep = 0; rep < 2; rep++) {
    int jb = threadIdx.x + rep * 256;
    unsigned int b = 0;
    if (at == 0) {
      const int4* arow = (const int4*)((const int*)adjv + (size_t)i * NN);
      int4 a0 = arow[jb * 2 + 0];
      int4 a1 = arow[jb * 2 + 1];
      b |= (a0.x > 0) ? 1u : 0u;  b |= (a0.y > 0) ? 2u : 0u;
      b |= (a0.z > 0) ? 4u : 0u;  b |= (a0.w > 0) ? 8u : 0u;
      b |= (a1.x > 0) ? 16u : 0u; b |= (a1.y > 0) ? 32u : 0u;
      b |= (a1.z > 0) ? 64u : 0u; b |= (a1.w > 0) ? 128u : 0u;
    } else if (at == 1) {
      const float* arow = (const float*)adjv + (size_t)i * NN + jb * 8;
      for (int t = 0; t < 8; t++) b |= (arow[t] > 0.5f) ? (1u << t) : 0u;
    } else {
      const unsigned short* arow = (const unsigned short*)adjv + (size_t)i * NN + jb * 8;
      for (int t = 0; t < 8; t++) b |= (bf2f(arow[t]) > 0.5f) ? (1u << t) : 0u;
    }
    bm[(size_t)i * 512 + jb] = (unsigned char)b;
  }
}

// ---------------- K1: wh = h@Wh + bWh. v4: LDS-staged h tile (16x256, one coalesced
// pass, 1 VMEM instr/thread) -> inner loop reads broadcast ds_read_b128 instead of
// 256 wave-uniform global loads/thread (VMEM 320 -> 65). Arithmetic order unchanged.
template <typename T>
__device__ __forceinline__ void wh_body(const T* h, const T* Wh, const T* bWh,
    const T* a_src, const T* a_dst, const T* a_b,
    unsigned short* __restrict__ Bp1, float* __restrict__ ssrc1, float* __restrict__ sdst1,
    float (*hs)[260], float (*wp)[16][260], float* av0, float* av1) {
  const int tid = threadIdx.x;
  const int w = tid >> 6, lane = tid & 63;
  const int head = w & 3, kq = w >> 2;
  const int rb = blockIdx.x;       // 0..255, 16 rows each
  const int R0 = rb * 16;
  const int d = lane;
  // Phase A: stage h tile (16 rows x 256) + attention vectors
  {
    const int r = tid >> 6, c4 = (tid & 63) * 4;
    float hv4[4];
    ld4(h + (size_t)(R0 + r) * 256 + c4, hv4);
    hs[r][c4 + 0] = hv4[0]; hs[r][c4 + 1] = hv4[1];
    hs[r][c4 + 2] = hv4[2]; hs[r][c4 + 3] = hv4[3];
  }
  if (tid < 256) av0[tid] = ld(a_src, tid);
  else if (tid < 512) av1[tid - 256] = ld(a_dst, tid - 256);
  __syncthreads();
  // Phase B: partial GEMM, this wave covers k in [kq*64, kq*64+64)
  float acc[16];
  float bv = (kq == 0) ? ld(bWh, head * 64 + d) : 0.f;
#pragma unroll
  for (int r = 0; r < 16; r++) acc[r] = bv;
  const int k0 = kq * 64;
  for (int kb = 0; kb < 8; kb++) {
    float wv[8];
#pragma unroll
    for (int j = 0; j < 8; j++)
      wv[j] = ld(Wh, (size_t)(head * 256 + k0 + kb * 8 + j) * 64 + d);
#pragma unroll
    for (int r = 0; r < 16; r++) {
      float4 ha = *(const float4*)(&hs[r][k0 + kb * 8]);
      float4 hb = *(const float4*)(&hs[r][k0 + kb * 8 + 4]);
      acc[r] = fmaf(ha.x, wv[0], acc[r]);
      acc[r] = fmaf(ha.y, wv[1], acc[r]);
      acc[r] = fmaf(ha.z, wv[2], acc[r]);
      acc[r] = fmaf(ha.w, wv[3], acc[r]);
      acc[r] = fmaf(hb.x, wv[4], acc[r]);
      acc[r] = fmaf(hb.y, wv[5], acc[r]);
      acc[r] = fmaf(hb.z, wv[6], acc[r]);
      acc[r] = fmaf(hb.w, wv[7], acc[r]);
    }
  }
  // two-slot combine: kq {2,3} write slots {0,1}; kq {0,1} add; pack sums both slots.
  if (kq >= 2) {
#pragma unroll
    for (int r = 0; r < 16; r++) wp[kq - 2][r][head * 64 + d] = acc[r];
  }
  __syncthreads();
  if (kq < 2) {
#pragma unroll
    for (int r = 0; r < 16; r++) wp[kq][r][head * 64 + d] += acc[r];
  }
  __syncthreads();
  // pack phase (parallel): tids 0-511 write Bp1 int4 units; 512-575 compute dots.
  if (tid < 512) {
    const int hh = tid >> 7, tt = (tid >> 5) & 3, lnh = tid & 31;
    const int q2 = (rb & 1) * 2 + (lnh >> 4);
    const int ln = q2 * 16 + (lnh & 15);
    const int dd = tt * 16 + (lnh & 15);
    const int rbase = (lnh >> 4) * 8;
    float v[8];
#pragma unroll
    for (int jj = 0; jj < 8; jj++)
      v[jj] = wp[0][rbase + jj][hh * 64 + dd] + wp[1][rbase + jj][hh * 64 + dd];
    i4s8 s;
    s.i.x = cvtpk(v[0], v[1]); s.i.y = cvtpk(v[2], v[3]);
    s.i.z = cvtpk(v[4], v[5]); s.i.w = cvtpk(v[6], v[7]);
    const int kb = rb >> 1;
    *(int4*)(Bp1 + ((((size_t)hh * 128 + kb) * 4 + tt) * 64 + ln) * 8) = s.i;
  } else if (tid < 576) {
    const int t2 = tid - 512;
    const int hh = t2 >> 4, r = t2 & 15;
    float ps = 0.f, pd = 0.f;
    for (int c = 0; c < 64; c++) {
      float wv2 = wp[0][r][hh * 64 + c] + wp[1][r][hh * 64 + c];
      ps = fmaf(wv2, av0[hh * 64 + c], ps);
      pd = fmaf(wv2, av1[hh * 64 + c], pd);
    }
    ssrc1[hh * NN + R0 + r] = ps + ld(a_b, hh);
    sdst1[hh * NN + R0 + r] = pd;
  }
}
__global__ __launch_bounds__(1024, 4) void k_wh(const void* h, const void* Wh, const void* bWh,
    const void* a_src, const void* a_dst, const void* a_b, const int* __restrict__ flags,
    unsigned short* Bp1, float* ssrc1, float* sdst1) {
  __shared__ float hs[16][260];
  __shared__ float wp[2][16][260];
  __shared__ float av0[256], av1[256];
  if (flags[0])
    wh_body<unsigned short>((const unsigned short*)h, (const unsigned short*)Wh,
        (const unsigned short*)bWh, (const unsigned short*)a_src,
        (const unsigned short*)a_dst, (const unsigned short*)a_b, Bp1, ssrc1, sdst1,
        hs, wp, av0, av1);
  else
    wh_body<float>((const float*)h, (const float*)Wh, (const float*)bWh, (const float*)a_src,
        (const float*)a_dst, (const float*)a_b, Bp1, ssrc1, sdst1, hs, wp, av0, av1);
}

// ---------------- K2-new: layer-1 attention. Grid 256 = 128 rowblocks(32 rows) x 2 kb-halves.
// 1024 thr = 16 waves = 4 heads x 4 slices(16 kb). Two A-frags/wave share every B load.
__global__ __launch_bounds__(1024, 4) void k_att1s(
    const unsigned char* __restrict__ bm, const float* __restrict__ ssrc,
    const float* __restrict__ sdst, const short8* __restrict__ Bp,
    float* __restrict__ part, float* __restrict__ partl) {
  const int rb = blockIdx.x & 127;
  const int half = blockIdx.x >> 7;
  const int tid = threadIdx.x;
  const int w = tid >> 6;
  const int head = w & 3;
  const int sl = w >> 2;  // 0..3: 16-kb slice within this half
  const int lane = tid & 63;
  const int r15 = lane & 15, quad = lane >> 4;
  const int row0 = rb * 32 + r15;
  const int row1 = row0 + 16;
  const float si0 = ssrc[head * NN + row0];
  const float si1 = ssrc[head * NN + row1];
  const unsigned char* bmr0 = bm + (size_t)row0 * 512;
  const unsigned char* bmr1 = bm + (size_t)row1 * 512;
  const float* sd = sdst + head * NN;
  const short8* Bh = Bp + (size_t)head * 128 * 4 * 64;
  f32x4 acc0[4], acc1[4];
#pragma unroll
  for (int t = 0; t < 4; t++) { acc0[t] = (f32x4){0,0,0,0}; acc1[t] = (f32x4){0,0,0,0}; }
  float ls0 = 0.f, ls1 = 0.f;
  const int kb0 = half * 64 + sl * 16;
  for (int g = 0; g < 4; g++) {          // 4 kb per group, bm fetched as int4
    const int kbg = kb0 + g * 4;
    int4 u0 = *(const int4*)(bmr0 + kbg * 4);
    int4 u1 = *(const int4*)(bmr1 + kbg * 4);
    int wd0[4] = {u0.x, u0.y, u0.z, u0.w};
    int wd1[4] = {u1.x, u1.y, u1.z, u1.w};
#pragma unroll
    for (int kk = 0; kk < 4; kk++) {
      const int kb = kbg + kk;
      const int j0 = kb * 32 + quad * 8;
      float4 q0 = *(const float4*)(sd + j0);
      float4 q1 = *(const float4*)(sd + j0 + 4);
      float sdv[8] = {q0.x, q0.y, q0.z, q0.w, q1.x, q1.y, q1.z, q1.w};
      unsigned int bits0 = (((unsigned int)wd0[kk]) >> (quad * 8)) & 0xffu;
      unsigned int bits1 = (((unsigned int)wd1[kk]) >> (quad * 8)) & 0xffu;
      float pe0[8], pe1[8];
#pragma unroll
      for (int jj = 0; jj < 8; jj++) {
        float t0 = si0 + sdv[jj];
        float e0 = __expf(fmaxf(t0, 0.2f * t0));
        pe0[jj] = ((bits0 >> jj) & 1u) ? e0 : 0.f;
        ls0 += pe0[jj];
        float t1 = si1 + sdv[jj];
        float e1 = __expf(fmaxf(t1, 0.2f * t1));
        pe1[jj] = ((bits1 >> jj) & 1u) ? e1 : 0.f;
        ls1 += pe1[jj];
      }
      i4s8 a0, a1;
      a0.i.x = cvtpk(pe0[0], pe0[1]); a0.i.y = cvtpk(pe0[2], pe0[3]);
      a0.i.z = cvtpk(pe0[4], pe0[5]); a0.i.w = cvtpk(pe0[6], pe0[7]);
      a1.i.x = cvtpk(pe1[0], pe1[1]); a1.i.y = cvtpk(pe1[2], pe1[3]);
      a1.i.z = cvtpk(pe1[4], pe1[5]); a1.i.w = cvtpk(pe1[6], pe1[7]);
      const short8* Bk = Bh + (size_t)kb * 256 + lane;
      short8 bt[4];
      bt[0] = Bk[0]; bt[1] = Bk[64]; bt[2] = Bk[128]; bt[3] = Bk[192];
#pragma unroll
      for (int t = 0; t < 4; t++) {
        acc0[t] = __builtin_amdgcn_mfma_f32_16x16x32_bf16(a0.s, bt[t], acc0[t], 0, 0, 0);
        acc1[t] = __builtin_amdgcn_mfma_f32_16x16x32_bf16(a1.s, bt[t], acc1[t], 0, 0, 0);
      }
    }
  }
  ls0 += __shfl_xor(ls0, 16); ls0 += __shfl_xor(ls0, 32);
  ls1 += __shfl_xor(ls1, 16); ls1 += __shfl_xor(ls1, 32);
  // combine 4 slices via 8 slots (head x 2): slices {2,3} write, {0,1} add; out sums pair.
  __shared__ float accs[8][16][66];
  __shared__ float lsh[8][16];
#define DOPASS(AC, LSV, PASS)                                                  \
  do {                                                                         \
    if (sl >= 2) {                                                             \
      const int slot = head * 2 + (sl - 2);                                    \
      if (lane < 16) lsh[slot][lane] = (LSV);                                  \
      _Pragma("unroll") for (int t = 0; t < 4; t++)                            \
        _Pragma("unroll") for (int gg = 0; gg < 4; gg++)                       \
          accs[slot][quad * 4 + gg][t * 16 + r15] = (AC)[t][gg];               \
    }                                                                          \
    __syncthreads();                                                           \
    if (sl < 2) {                                                              \
      const int slot = head * 2 + sl;                                          \
      if (lane < 16) lsh[slot][lane] += (LSV);                                 \
      _Pragma("unroll") for (int t = 0; t < 4; t++)                            \
        _Pragma("unroll") for (int gg = 0; gg < 4; gg++)                       \
          accs[slot][quad * 4 + gg][t * 16 + r15] += (AC)[t][gg];              \
    }                                                                          \
    __syncthreads();                                                           \
    _Pragma("unroll") for (int idx = tid; idx < 4096; idx += 1024) {           \
      int r = idx >> 8, hc = idx & 255;                                        \
      int hh = hc >> 6, col = hc & 63;                                         \
      part[((size_t)half * NN + rb * 32 + (PASS) * 16 + r) * 256 + hc] =       \
          accs[hh * 2][r][col] + accs[hh * 2 + 1][r][col];                     \
    }                                                                          \
    if (tid < 64)                                                              \
      partl[((size_t)half * 4 + (tid >> 4)) * NN + rb * 32 + (PASS) * 16 +     \
            (tid & 15)] = lsh[(tid >> 4) * 2][tid & 15] +                      \
                          lsh[(tid >> 4) * 2 + 1][tid & 15];                   \
    __syncthreads();                                                           \
  } while (0)
  DOPASS(acc0, ls0, 0);
  DOPASS(acc1, ls1, 1);
#undef DOPASS
}

// ---------------- K2-fin: sum the 2 kb-half partials, normalize, elu, pack bf16.
__global__ __launch_bounds__(256) void k_att1f(const float* __restrict__ part,
    const float* __restrict__ partl, unsigned short* __restrict__ x2) {
  const int idx = blockIdx.x * 256 + threadIdx.x;  // 262144 = 4096 rows x 64 col-quads
  const int row = idx >> 6;
  const int c4 = (idx & 63) * 4;
  const int head = c4 >> 6;
  const size_t off = (size_t)row * 256 + c4;
  float4 p0 = *(const float4*)(part + off);
  float4 p1 = *(const float4*)(part + (size_t)NN * 256 + off);
  float lt = partl[(size_t)head * NN + row] + partl[(size_t)(4 + head) * NN + row];
  float rl = (lt > 0.f) ? 1.f / lt : 0.f;
  float v0 = (p0.x + p1.x) * rl, v1 = (p0.y + p1.y) * rl;
  float v2 = (p0.z + p1.z) * rl, v3 = (p0.w + p1.w) * rl;
  v0 = v0 > 0.f ? v0 : __expf(v0) - 1.f;
  v1 = v1 > 0.f ? v1 : __expf(v1) - 1.f;
  v2 = v2 > 0.f ? v2 : __expf(v2) - 1.f;
  v3 = v3 > 0.f ? v3 : __expf(v3) - 1.f;
  uint2 st; st.x = cvtpk(v0, v1); st.y = cvtpk(v2, v3);
  *(uint2*)(x2 + off) = st;
}

// ---------------- K2-old (fallback if workspace too small for partials)
__global__ __launch_bounds__(1024) void k_att1(
    const unsigned char* __restrict__ bm, const float* __restrict__ ssrc,
    const float* __restrict__ sdst, const short8* __restrict__ Bp,
    unsigned short* __restrict__ x2) {
  const int rb = blockIdx.x;
  const int tid = threadIdx.x;
  const int w = tid >> 6;
  const int head = w & 3;
  const int slice = w >> 2;
  const int lane = tid & 63;
  const int r15 = lane & 15, quad = lane >> 4;
  const int row = rb * 16 + r15;
  const float si = ssrc[head * NN + row];
  const unsigned char* bmrow = bm + (size_t)row * 512;
  const float* sd = sdst + head * NN;
  const short8* Bh = Bp + (size_t)head * 128 * 4 * 64;
  f32x4 acc0 = {0, 0, 0, 0}, acc1 = {0, 0, 0, 0}, acc2 = {0, 0, 0, 0}, acc3 = {0, 0, 0, 0};
  float lsum = 0.f;
  const int kb0 = slice * 32;
  for (int kb = kb0; kb < kb0 + 32; kb++) {
    const int j0 = kb * 32 + quad * 8;
    unsigned int bits = bmrow[kb * 4 + quad];
    float4 q0 = *(const float4*)(sd + j0);
    float4 q1 = *(const float4*)(sd + j0 + 4);
    float sdv[8] = {q0.x, q0.y, q0.z, q0.w, q1.x, q1.y, q1.z, q1.w};
    short8 af;
#pragma unroll
    for (int jj = 0; jj < 8; jj++) {
      float t = si + sdv[jj];
      float lr = fmaxf(t, 0.2f * t);
      float e = __expf(lr);
      float pe = ((bits >> jj) & 1u) ? e : 0.0f;
      lsum += pe;
      af[jj] = (short)f2bf(pe);
    }
    const short8* Bk = Bh + (size_t)kb * 256 + lane;
    short8 b0 = Bk[0], b1 = Bk[64], b2 = Bk[128], b3 = Bk[192];
    acc0 = __builtin_amdgcn_mfma_f32_16x16x32_bf16(af, b0, acc0, 0, 0, 0);
    acc1 = __builtin_amdgcn_mfma_f32_16x16x32_bf16(af, b1, acc1, 0, 0, 0);
    acc2 = __builtin_amdgcn_mfma_f32_16x16x32_bf16(af, b2, acc2, 0, 0, 0);
    acc3 = __builtin_amdgcn_mfma_f32_16x16x32_bf16(af, b3, acc3, 0, 0, 0);
  }
  lsum += __shfl_xor(lsum, 16);
  lsum += __shfl_xor(lsum, 32);
  __shared__ float accs[8][16][66];
  __shared__ float ls[8][16];
  if (slice >= 2) {
    const int slot = w - 8;
    if (lane < 16) ls[slot][lane] = lsum;
#pragma unroll
    for (int g = 0; g < 4; g++) {
      int r = quad * 4 + g;
      accs[slot][r][ 0 + r15] = acc0[g];
      accs[slot][r][16 + r15] = acc1[g];
      accs[slot][r][32 + r15] = acc2[g];
      accs[slot][r][48 + r15] = acc3[g];
    }
  }
  __syncthreads();
  if (slice < 2) {
    const int slot = w;
    if (lane < 16) ls[slot][lane] += lsum;
#pragma unroll
    for (int g = 0; g < 4; g++) {
      int r = quad * 4 + g;
      accs[slot][r][ 0 + r15] += acc0[g];
      accs[slot][r][16 + r15] += acc1[g];
      accs[slot][r][32 + r15] += acc2[g];
      accs[slot][r][48 + r15] += acc3[g];
    }
  }
  __syncthreads();
#pragma unroll
  for (int c = tid; c < 4096; c += 1024) {
    int r = c >> 8, hc = c & 255;
    int hh = hc >> 6, col = hc & 63;
    float s = accs[hh][r][col] + accs[hh + 4][r][col];
    float lt = ls[hh][r] + ls[hh + 4][r];
    float v = (lt > 0.f) ? s / lt : 0.f;
    v = v > 0.f ? v : __expf(v) - 1.f;
    x2[(size_t)(rb * 16 + r) * 256 + hc] = f2bf(v);
  }
}

// ---------------- K3: wo = x2@Wo + bWo. v3: LDS-staged x2 tile (same recipe as k_wh).
template <typename T>
__device__ __forceinline__ void wo_body(const unsigned short* x2, const T* Wo, const T* bWo,
    const T* ao_src, const T* ao_dst, const T* ao_b,
    unsigned short* __restrict__ Bp2, float* __restrict__ ssrc2, float* __restrict__ sdst2,
    float (*xs)[260], float (*wp)[16][68], float* av) {
  const int tid = threadIdx.x;
  const int w = tid >> 6, lane = tid & 63;
  const int rg = w & 3, kq = w >> 2;
  const int rb = blockIdx.x;         // 0..255, 16 rows each
  const int d = lane;
  // Phase A: stage x2 tile (16 rows x 256 bf16 -> fp32 LDS)
  {
    const int r = tid >> 6, c4 = (tid & 63) * 4;
    float hv4[4];
    ld4(x2 + (size_t)(rb * 16 + r) * 256 + c4, hv4);
    xs[r][c4 + 0] = hv4[0]; xs[r][c4 + 1] = hv4[1];
    xs[r][c4 + 2] = hv4[2]; xs[r][c4 + 3] = hv4[3];
  }
  if (tid < 64) av[tid] = ld(ao_src, tid);
  else if (tid < 128) av[tid] = ld(ao_dst, tid - 64);
  __syncthreads();
  const int rr = rg * 4;             // this wave's 4 local rows
  float acc[4];
  float bv = (kq == 0) ? ld(bWo, d) : 0.f;
#pragma unroll
  for (int r = 0; r < 4; r++) acc[r] = bv;
  const int k0 = kq * 64;
  for (int kb = 0; kb < 8; kb++) {
    float wv[8];
#pragma unroll
    for (int j = 0; j < 8; j++)
      wv[j] = ld(Wo, (size_t)(k0 + kb * 8 + j) * 64 + d);
#pragma unroll
    for (int r = 0; r < 4; r++) {
      float4 ha = *(const float4*)(&xs[rr + r][k0 + kb * 8]);
      float4 hb = *(const float4*)(&xs[rr + r][k0 + kb * 8 + 4]);
      acc[r] = fmaf(ha.x, wv[0], acc[r]);
      acc[r] = fmaf(ha.y, wv[1], acc[r]);
      acc[r] = fmaf(ha.z, wv[2], acc[r]);
      acc[r] = fmaf(ha.w, wv[3], acc[r]);
      acc[r] = fmaf(hb.x, wv[4], acc[r]);
      acc[r] = fmaf(hb.y, wv[5], acc[r]);
      acc[r] = fmaf(hb.z, wv[6], acc[r]);
      acc[r] = fmaf(hb.w, wv[7], acc[r]);
    }
  }
  if (kq >= 2) {
#pragma unroll
    for (int r = 0; r < 4; r++) wp[kq - 2][rr + r][d] = acc[r];
  }
  __syncthreads();
  if (kq < 2) {
#pragma unroll
    for (int r = 0; r < 4; r++) wp[kq][rr + r][d] += acc[r];
  }
  __syncthreads();
  if (tid < 128) {
    const int tt = tid >> 5, lnh = tid & 31;
    const int q2 = (rb & 1) * 2 + (lnh >> 4);
    const int ln = q2 * 16 + (lnh & 15);
    const int dd = tt * 16 + (lnh & 15);
    const int rbase = (lnh >> 4) * 8;
    float v[8];
#pragma unroll
    for (int jj = 0; jj < 8; jj++)
      v[jj] = wp[0][rbase + jj][dd] + wp[1][rbase + jj][dd];
    i4s8 s;
    s.i.x = cvtpk(v[0], v[1]); s.i.y = cvtpk(v[2], v[3]);
    s.i.z = cvtpk(v[4], v[5]); s.i.w = cvtpk(v[6], v[7]);
    const int kb = rb >> 1;
    *(int4*)(Bp2 + (((size_t)kb * 4 + tt) * 64 + ln) * 8) = s.i;
  } else if (tid < 144) {
    const int r = tid - 128;
    float ps = 0.f, pd = 0.f;
    for (int c = 0; c < 64; c++) {
      float wv2 = wp[0][r][c] + wp[1][r][c];
      ps = fmaf(wv2, av[c], ps);
      pd = fmaf(wv2, av[64 + c], pd);
    }
    ssrc2[(size_t)rb * 16 + r] = ps + ld(ao_b, 0);
    sdst2[(size_t)rb * 16 + r] = pd;
  }
}
__global__ __launch_bounds__(1024, 4) void k_wo(const unsigned short* __restrict__ x2,
    const void* Wo, const void* bWo, const void* ao_src, const void* ao_dst, const void* ao_b,
    const int* __restrict__ flags, unsigned short* Bp2, float* ssrc2, float* sdst2) {
  __shared__ float xs[16][260];
  __shared__ float wp[2][16][68];
  __shared__ float av[128];
  if (flags[0])
    wo_body<unsigned short>(x2, (const unsigned short*)Wo, (const unsigned short*)bWo,
        (const unsigned short*)ao_src, (const unsigned short*)ao_dst,
        (const unsigned short*)ao_b, Bp2, ssrc2, sdst2, xs, wp, av);
  else
    wo_body<float>(x2, (const float*)Wo, (const float*)bWo, (const float*)ao_src,
        (const float*)ao_dst, (const float*)ao_b, Bp2, ssrc2, sdst2, xs, wp, av);
}

// ---------------- K4: layer-2 attention (1 head), 16 rows/block, 16-way j-split.
__global__ __launch_bounds__(1024) void k_att2(
    const unsigned char* __restrict__ bm, const float* __restrict__ ssrc,
    const float* __restrict__ sdst, const short8* __restrict__ Bp,
    const int* __restrict__ flags, void* __restrict__ outv) {
  const int rb = blockIdx.x;
  const int tid = threadIdx.x;
  const int w = tid >> 6;  // j-slice 0..15
  const int lane = tid & 63;
  const int r15 = lane & 15, quad = lane >> 4;
  const int row = rb * 16 + r15;
  const float si = ssrc[row];
  const unsigned char* bmrow = bm + (size_t)row * 512;
  f32x4 acc0 = {0, 0, 0, 0}, acc1 = {0, 0, 0, 0}, acc2 = {0, 0, 0, 0}, acc3 = {0, 0, 0, 0};
  float lsum = 0.f;
  const int kb0 = w * 8;
#pragma unroll
  for (int g = 0; g < 2; g++) {
    int4 ubm = *(const int4*)(bmrow + (kb0 + g * 4) * 4);
    int wds[4] = {ubm.x, ubm.y, ubm.z, ubm.w};
#pragma unroll
    for (int kk = 0; kk < 4; kk++) {
      const int kb = kb0 + g * 4 + kk;
      const int j0 = kb * 32 + quad * 8;
      unsigned int bits = (((unsigned int)wds[kk]) >> (quad * 8)) & 0xffu;
      float4 q0 = *(const float4*)(sdst + j0);
      float4 q1 = *(const float4*)(sdst + j0 + 4);
      float sdv[8] = {q0.x, q0.y, q0.z, q0.w, q1.x, q1.y, q1.z, q1.w};
      float pe[8];
#pragma unroll
      for (int jj = 0; jj < 8; jj++) {
        float t = si + sdv[jj];
        float e = __expf(fmaxf(t, 0.2f * t));
        pe[jj] = ((bits >> jj) & 1u) ? e : 0.f;
        lsum += pe[jj];
      }
      i4s8 a;
      a.i.x = cvtpk(pe[0], pe[1]); a.i.y = cvtpk(pe[2], pe[3]);
      a.i.z = cvtpk(pe[4], pe[5]); a.i.w = cvtpk(pe[6], pe[7]);
      const short8* Bk = Bp + (size_t)kb * 256 + lane;
      short8 b0 = Bk[0], b1 = Bk[64], b2 = Bk[128], b3 = Bk[192];
      acc0 = __builtin_amdgcn_mfma_f32_16x16x32_bf16(a.s, b0, acc0, 0, 0, 0);
      acc1 = __builtin_amdgcn_mfma_f32_16x16x32_bf16(a.s, b1, acc1, 0, 0, 0);
      acc2 = __builtin_amdgcn_mfma_f32_16x16x32_bf16(a.s, b2, acc2, 0, 0, 0);
      acc3 = __builtin_amdgcn_mfma_f32_16x16x32_bf16(a.s, b3, acc3, 0, 0, 0);
    }
  }
  lsum += __shfl_xor(lsum, 16);
  lsum += __shfl_xor(lsum, 32);
  __shared__ float accs[8][16][66];
  __shared__ float ls2[8][16];
  if (w >= 8) {
    const int slot = w - 8;
    if (lane < 16) ls2[slot][lane] = lsum;
#pragma unroll
    for (int g = 0; g < 4; g++) {
      int r = quad * 4 + g;
      accs[slot][r][ 0 + r15] = acc0[g];
      accs[slot][r][16 + r15] = acc1[g];
      accs[slot][r][32 + r15] = acc2[g];
      accs[slot][r][48 + r15] = acc3[g];
    }
  }
  __syncthreads();
  if (w < 8) {
    const int slot = w;
    if (lane < 16) ls2[slot][lane] += lsum;
#pragma unroll
    for (int g = 0; g < 4; g++) {
      int r = quad * 4 + g;
      accs[slot][r][ 0 + r15] += acc0[g];
      accs[slot][r][16 + r15] += acc1[g];
      accs[slot][r][32 + r15] += acc2[g];
      accs[slot][r][48 + r15] += acc3[g];
    }
  }
  __syncthreads();
  {
    const int r = tid >> 6, col = tid & 63;
    float s = 0.f, lt = 0.f;
#pragma unroll
    for (int k = 0; k < 8; k++) { s += accs[k][r][col]; lt += ls2[k][r]; }
    float v = (lt > 0.f) ? s / lt : 0.f;
    v = v > 0.f ? v : __expf(v) - 1.f;
    size_t idx = (size_t)(rb * 16 + r) * 64 + col;
    if (flags[0]) ((unsigned short*)outv)[idx] = f2bf(v);
    else          ((float*)outv)[idx] = v;
  }
}

extern "C" void kernel_launch(void* const* d_in, const int* in_sizes, int n_in,
                              void* d_out, int out_size, void* d_ws, size_t ws_size,
                              hipStream_t stream) {
  const void* h      = d_in[0];
  const void* adj    = d_in[1];
  const void* Wh     = d_in[2];
  const void* bWh    = d_in[3];
  const void* a_src  = d_in[4];
  const void* a_dst  = d_in[5];
  const void* a_b    = d_in[6];
  const void* Wo     = d_in[7];
  const void* bWo    = d_in[8];
  const void* ao_src = d_in[9];
  const void* ao_dst = d_in[10];
  const void* ao_b   = d_in[11];

  size_t need_old = 16 + (size_t)NN * 512 + (size_t)NHEADS * NN * HID * 2 +
                    (size_t)NN * 256 * 2 + (size_t)NN * 64 * 2 +
                    (size_t)NHEADS * NN * 8 + (size_t)NN * 8;
  size_t need_new = need_old + (size_t)2 * NN * 256 * 4 + (size_t)2 * 4 * NN * 4;
  hipMemsetAsync(d_out, 0x41, (size_t)out_size * 2, stream);
  if (ws_size < need_old) {
    hipMemsetAsync(d_out, 0x45, (size_t)out_size * 2, stream);
    return;
  }
  const bool big = ws_size >= need_new;
  unsigned char* ws = (unsigned char*)d_ws;
  int* flags = (int*)ws;                        ws += 16;
  unsigned char* bmp = ws;                      ws += (size_t)NN * 512;               // 2 MB
  unsigned short* Bp1 = (unsigned short*)ws;    ws += (size_t)NHEADS * NN * HID * 2;  // 2 MB
  unsigned short* x2  = (unsigned short*)ws;    ws += (size_t)NN * 256 * 2;           // 2 MB
  unsigned short* Bp2 = (unsigned short*)ws;    ws += (size_t)NN * 64 * 2;            // 512 KB
  float* ssrc1 = (float*)ws;                    ws += (size_t)NHEADS * NN * 4;
  float* sdst1 = (float*)ws;                    ws += (size_t)NHEADS * NN * 4;
  float* ssrc2 = (float*)ws;                    ws += (size_t)NN * 4;
  float* sdst2 = (float*)ws;                    ws += (size_t)NN * 4;
  float* part  = (float*)ws;                    ws += (size_t)2 * NN * 256 * 4;       // 8 MB
  float* partl = (float*)ws;                    ws += (size_t)2 * 4 * NN * 4;         // 128 KB

  k_probe<<<dim3(1),    dim3(256),  0, stream>>>(h, adj, flags);
  k_bm   <<<dim3(4096), dim3(256),  0, stream>>>(adj, flags, bmp);
  k_wh   <<<dim3(256),  dim3(1024), 0, stream>>>(h, Wh, bWh, a_src, a_dst, a_b, flags,
                                                 Bp1, ssrc1, sdst1);
  if (big) {
    k_att1s<<<dim3(256),  dim3(1024), 0, stream>>>(bmp, ssrc1, sdst1, (const short8*)Bp1,
                                                   part, partl);
    k_att1f<<<dim3(1024), dim3(256),  0, stream>>>(part, partl, x2);
  } else {
    k_att1<<<dim3(256), dim3(1024), 0, stream>>>(bmp, ssrc1, sdst1, (const short8*)Bp1, x2);
  }
  k_wo   <<<dim3(256),  dim3(1024), 0, stream>>>(x2, Wo, bWo, ao_src, ao_dst, ao_b, flags,
                                                 Bp2, ssrc2, sdst2);
  k_att2 <<<dim3(256),  dim3(1024), 0, stream>>>(bmp, ssrc2, sdst2, (const short8*)Bp2,
                                                 flags, d_out);
}

// Round 8
// 179.180 us; speedup vs baseline: 1.2231x; 1.0269x over previous
//
#include <hip/hip_runtime.h>

#define NN 4096
#define NHEADS 4
#define HID 64
#define INDIM 256

using short8 = __attribute__((ext_vector_type(8))) short;
using f32x4  = __attribute__((ext_vector_type(4))) float;

union f32u { float f; unsigned int u; };
union i4s8 { int4 i; short8 s; };

__device__ __forceinline__ float bf2f(unsigned short s) {
  f32u x; x.u = ((unsigned int)s) << 16; return x.f;
}
__device__ __forceinline__ unsigned short f2bf(float f) {
  f32u x; x.f = f;
  unsigned int r = x.u + 0x7fffu + ((x.u >> 16) & 1u);
  return (unsigned short)(r >> 16);
}
// packed f32x2 -> bf16x2 (RNE, same as f2bf) in one instruction
__device__ __forceinline__ unsigned int cvtpk(float lo, float hi) {
  unsigned int r;
  asm("v_cvt_pk_bf16_f32 %0, %1, %2" : "=v"(r) : "v"(lo), "v"(hi));
  return r;
}

// overloaded external-input loaders
__device__ __forceinline__ float ld(const unsigned short* p, size_t i) { return bf2f(p[i]); }
__device__ __forceinline__ float ld(const float* p, size_t i) { return p[i]; }
// 4-element loader (8B for bf16, 16B for fp32) — p must be 4-elem aligned
__device__ __forceinline__ void ld4(const unsigned short* p, float* out) {
  short4 v = *(const short4*)p;
  out[0] = bf2f((unsigned short)v.x); out[1] = bf2f((unsigned short)v.y);
  out[2] = bf2f((unsigned short)v.z); out[3] = bf2f((unsigned short)v.w);
}
__device__ __forceinline__ void ld4(const float* p, float* out) {
  float4 a = *(const float4*)p;
  out[0] = a.x; out[1] = a.y; out[2] = a.z; out[3] = a.w;
}

// ---------------- K0: adj -> bitmask bytes bm[i][j>>3]; dtype probe folded in.
// Each block derives `at` locally (first 1 KB of adj, L2-broadcast). Block 0 also
// probes h and publishes flags[] for downstream kernels (k_probe dispatch removed).
__global__ __launch_bounds__(256) void k_bm(const void* adjv, const void* hv,
                                            int* __restrict__ flags,
                                            unsigned char* __restrict__ bm) {
  __shared__ int s_at;
  const int tid = threadIdx.x;
  if (tid == 0) s_at = 0;
  __syncthreads();
  const unsigned int* au = (const unsigned int*)adjv;
  unsigned int wv = au[tid];
  if ((wv & 0xFFFFu) == 0x3F80u) atomicOr(&s_at, 2);       // bf16 pair (1.0, x)
  else if (wv == 0x3F800000u) atomicOr(&s_at, 1);          // float32 1.0
  __syncthreads();
  const int at = (s_at & 2) ? 2 : (s_at & 1);
  const int i = blockIdx.x;
  if (i == 0 && tid < 64) {
    const unsigned short* hu = (const unsigned short*)hv;
    int bad = 0;
    for (int t = tid; t < 256; t += 64) {
      float v = bf2f(hu[t]);
      if (!(v > -1000.f && v < 1000.f)) bad = 1;           // fp32 halves look huge as bf16
    }
    unsigned long long m = __ballot(bad);
    if (tid == 0) { flags[0] = m ? 0 : 1; flags[1] = at; }
  }
#pragma unroll
  for (int rep = 0; rep < 2; rep++) {
    int jb = tid + rep * 256;
    unsigned int b = 0;
    if (at == 0) {
      const int4* arow = (const int4*)((const int*)adjv + (size_t)i * NN);
      int4 a0 = arow[jb * 2 + 0];
      int4 a1 = arow[jb * 2 + 1];
      b |= (a0.x > 0) ? 1u : 0u;  b |= (a0.y > 0) ? 2u : 0u;
      b |= (a0.z > 0) ? 4u : 0u;  b |= (a0.w > 0) ? 8u : 0u;
      b |= (a1.x > 0) ? 16u : 0u; b |= (a1.y > 0) ? 32u : 0u;
      b |= (a1.z > 0) ? 64u : 0u; b |= (a1.w > 0) ? 128u : 0u;
    } else if (at == 1) {
      const float* arow = (const float*)adjv + (size_t)i * NN + jb * 8;
      for (int t = 0; t < 8; t++) b |= (arow[t] > 0.5f) ? (1u << t) : 0u;
    } else {
      const unsigned short* arow = (const unsigned short*)adjv + (size_t)i * NN + jb * 8;
      for (int t = 0; t < 8; t++) b |= (bf2f(arow[t]) > 0.5f) ? (1u << t) : 0u;
    }
    bm[(size_t)i * 512 + jb] = (unsigned char)b;
  }
}

// ---------------- K1: wh = h@Wh + bWh. LDS-staged h tile (16x256), 16 waves =
// 4 heads x 4 k-quarters, two-slot LDS combine, pack phase writes int4 Bp1 units.
template <typename T>
__device__ __forceinline__ void wh_body(const T* h, const T* Wh, const T* bWh,
    const T* a_src, const T* a_dst, const T* a_b,
    unsigned short* __restrict__ Bp1, float* __restrict__ ssrc1, float* __restrict__ sdst1,
    float (*hs)[260], float (*wp)[16][260], float* av0, float* av1) {
  const int tid = threadIdx.x;
  const int w = tid >> 6, lane = tid & 63;
  const int head = w & 3, kq = w >> 2;
  const int rb = blockIdx.x;       // 0..255, 16 rows each
  const int R0 = rb * 16;
  const int d = lane;
  // Phase A: stage h tile (16 rows x 256) + attention vectors
  {
    const int r = tid >> 6, c4 = (tid & 63) * 4;
    float hv4[4];
    ld4(h + (size_t)(R0 + r) * 256 + c4, hv4);
    hs[r][c4 + 0] = hv4[0]; hs[r][c4 + 1] = hv4[1];
    hs[r][c4 + 2] = hv4[2]; hs[r][c4 + 3] = hv4[3];
  }
  if (tid < 256) av0[tid] = ld(a_src, tid);
  else if (tid < 512) av1[tid - 256] = ld(a_dst, tid - 256);
  __syncthreads();
  // Phase B: partial GEMM, this wave covers k in [kq*64, kq*64+64)
  float acc[16];
  float bv = (kq == 0) ? ld(bWh, head * 64 + d) : 0.f;
#pragma unroll
  for (int r = 0; r < 16; r++) acc[r] = bv;
  const int k0 = kq * 64;
  for (int kb = 0; kb < 8; kb++) {
    float wv[8];
#pragma unroll
    for (int j = 0; j < 8; j++)
      wv[j] = ld(Wh, (size_t)(head * 256 + k0 + kb * 8 + j) * 64 + d);
#pragma unroll
    for (int r = 0; r < 16; r++) {
      float4 ha = *(const float4*)(&hs[r][k0 + kb * 8]);
      float4 hb = *(const float4*)(&hs[r][k0 + kb * 8 + 4]);
      acc[r] = fmaf(ha.x, wv[0], acc[r]);
      acc[r] = fmaf(ha.y, wv[1], acc[r]);
      acc[r] = fmaf(ha.z, wv[2], acc[r]);
      acc[r] = fmaf(ha.w, wv[3], acc[r]);
      acc[r] = fmaf(hb.x, wv[4], acc[r]);
      acc[r] = fmaf(hb.y, wv[5], acc[r]);
      acc[r] = fmaf(hb.z, wv[6], acc[r]);
      acc[r] = fmaf(hb.w, wv[7], acc[r]);
    }
  }
  // two-slot combine: kq {2,3} write slots {0,1}; kq {0,1} add; pack sums both slots.
  if (kq >= 2) {
#pragma unroll
    for (int r = 0; r < 16; r++) wp[kq - 2][r][head * 64 + d] = acc[r];
  }
  __syncthreads();
  if (kq < 2) {
#pragma unroll
    for (int r = 0; r < 16; r++) wp[kq][r][head * 64 + d] += acc[r];
  }
  __syncthreads();
  // pack phase (parallel): tids 0-511 write Bp1 int4 units; 512-575 compute dots.
  if (tid < 512) {
    const int hh = tid >> 7, tt = (tid >> 5) & 3, lnh = tid & 31;
    const int q2 = (rb & 1) * 2 + (lnh >> 4);
    const int ln = q2 * 16 + (lnh & 15);
    const int dd = tt * 16 + (lnh & 15);
    const int rbase = (lnh >> 4) * 8;
    float v[8];
#pragma unroll
    for (int jj = 0; jj < 8; jj++)
      v[jj] = wp[0][rbase + jj][hh * 64 + dd] + wp[1][rbase + jj][hh * 64 + dd];
    i4s8 s;
    s.i.x = cvtpk(v[0], v[1]); s.i.y = cvtpk(v[2], v[3]);
    s.i.z = cvtpk(v[4], v[5]); s.i.w = cvtpk(v[6], v[7]);
    const int kb = rb >> 1;
    *(int4*)(Bp1 + ((((size_t)hh * 128 + kb) * 4 + tt) * 64 + ln) * 8) = s.i;
  } else if (tid < 576) {
    const int t2 = tid - 512;
    const int hh = t2 >> 4, r = t2 & 15;
    float ps = 0.f, pd = 0.f;
    for (int c = 0; c < 64; c++) {
      float wv2 = wp[0][r][hh * 64 + c] + wp[1][r][hh * 64 + c];
      ps = fmaf(wv2, av0[hh * 64 + c], ps);
      pd = fmaf(wv2, av1[hh * 64 + c], pd);
    }
    ssrc1[hh * NN + R0 + r] = ps + ld(a_b, hh);
    sdst1[hh * NN + R0 + r] = pd;
  }
}
__global__ __launch_bounds__(1024, 4) void k_wh(const void* h, const void* Wh, const void* bWh,
    const void* a_src, const void* a_dst, const void* a_b, const int* __restrict__ flags,
    unsigned short* Bp1, float* ssrc1, float* sdst1) {
  __shared__ float hs[16][260];
  __shared__ float wp[2][16][260];
  __shared__ float av0[256], av1[256];
  if (flags[0])
    wh_body<unsigned short>((const unsigned short*)h, (const unsigned short*)Wh,
        (const unsigned short*)bWh, (const unsigned short*)a_src,
        (const unsigned short*)a_dst, (const unsigned short*)a_b, Bp1, ssrc1, sdst1,
        hs, wp, av0, av1);
  else
    wh_body<float>((const float*)h, (const float*)Wh, (const float*)bWh, (const float*)a_src,
        (const float*)a_dst, (const float*)a_b, Bp1, ssrc1, sdst1, hs, wp, av0, av1);
}

// ---------------- K2: layer-1 attention. Grid 256 = 128 rowblocks(32 rows) x 2 kb-halves.
// 1024 thr = 16 waves = 4 heads x 4 slices(16 kb). Two A-frags/wave share every B load.
__global__ __launch_bounds__(1024, 4) void k_att1s(
    const unsigned char* __restrict__ bm, const float* __restrict__ ssrc,
    const float* __restrict__ sdst, const short8* __restrict__ Bp,
    float* __restrict__ part, float* __restrict__ partl) {
  const int rb = blockIdx.x & 127;
  const int half = blockIdx.x >> 7;
  const int tid = threadIdx.x;
  const int w = tid >> 6;
  const int head = w & 3;
  const int sl = w >> 2;  // 0..3: 16-kb slice within this half
  const int lane = tid & 63;
  const int r15 = lane & 15, quad = lane >> 4;
  const int row0 = rb * 32 + r15;
  const int row1 = row0 + 16;
  const float si0 = ssrc[head * NN + row0];
  const float si1 = ssrc[head * NN + row1];
  const unsigned char* bmr0 = bm + (size_t)row0 * 512;
  const unsigned char* bmr1 = bm + (size_t)row1 * 512;
  const float* sd = sdst + head * NN;
  const short8* Bh = Bp + (size_t)head * 128 * 4 * 64;
  f32x4 acc0[4], acc1[4];
#pragma unroll
  for (int t = 0; t < 4; t++) { acc0[t] = (f32x4){0,0,0,0}; acc1[t] = (f32x4){0,0,0,0}; }
  float ls0 = 0.f, ls1 = 0.f;
  const int kb0 = half * 64 + sl * 16;
  for (int g = 0; g < 4; g++) {          // 4 kb per group, bm fetched as int4
    const int kbg = kb0 + g * 4;
    int4 u0 = *(const int4*)(bmr0 + kbg * 4);
    int4 u1 = *(const int4*)(bmr1 + kbg * 4);
    int wd0[4] = {u0.x, u0.y, u0.z, u0.w};
    int wd1[4] = {u1.x, u1.y, u1.z, u1.w};
#pragma unroll
    for (int kk = 0; kk < 4; kk++) {
      const int kb = kbg + kk;
      const int j0 = kb * 32 + quad * 8;
      float4 q0 = *(const float4*)(sd + j0);
      float4 q1 = *(const float4*)(sd + j0 + 4);
      float sdv[8] = {q0.x, q0.y, q0.z, q0.w, q1.x, q1.y, q1.z, q1.w};
      unsigned int bits0 = (((unsigned int)wd0[kk]) >> (quad * 8)) & 0xffu;
      unsigned int bits1 = (((unsigned int)wd1[kk]) >> (quad * 8)) & 0xffu;
      float pe0[8], pe1[8];
#pragma unroll
      for (int jj = 0; jj < 8; jj++) {
        float t0 = si0 + sdv[jj];
        float e0 = __expf(fmaxf(t0, 0.2f * t0));
        pe0[jj] = ((bits0 >> jj) & 1u) ? e0 : 0.f;
        ls0 += pe0[jj];
        float t1 = si1 + sdv[jj];
        float e1 = __expf(fmaxf(t1, 0.2f * t1));
        pe1[jj] = ((bits1 >> jj) & 1u) ? e1 : 0.f;
        ls1 += pe1[jj];
      }
      i4s8 a0, a1;
      a0.i.x = cvtpk(pe0[0], pe0[1]); a0.i.y = cvtpk(pe0[2], pe0[3]);
      a0.i.z = cvtpk(pe0[4], pe0[5]); a0.i.w = cvtpk(pe0[6], pe0[7]);
      a1.i.x = cvtpk(pe1[0], pe1[1]); a1.i.y = cvtpk(pe1[2], pe1[3]);
      a1.i.z = cvtpk(pe1[4], pe1[5]); a1.i.w = cvtpk(pe1[6], pe1[7]);
      const short8* Bk = Bh + (size_t)kb * 256 + lane;
      short8 bt[4];
      bt[0] = Bk[0]; bt[1] = Bk[64]; bt[2] = Bk[128]; bt[3] = Bk[192];
#pragma unroll
      for (int t = 0; t < 4; t++) {
        acc0[t] = __builtin_amdgcn_mfma_f32_16x16x32_bf16(a0.s, bt[t], acc0[t], 0, 0, 0);
        acc1[t] = __builtin_amdgcn_mfma_f32_16x16x32_bf16(a1.s, bt[t], acc1[t], 0, 0, 0);
      }
    }
  }
  ls0 += __shfl_xor(ls0, 16); ls0 += __shfl_xor(ls0, 32);
  ls1 += __shfl_xor(ls1, 16); ls1 += __shfl_xor(ls1, 32);
  // combine 4 slices via 8 slots (head x 2): slices {2,3} write, {0,1} add; out sums pair.
  __shared__ float accs[8][16][66];
  __shared__ float lsh[8][16];
#define DOPASS(AC, LSV, PASS)                                                  \
  do {                                                                         \
    if (sl >= 2) {                                                             \
      const int slot = head * 2 + (sl - 2);                                    \
      if (lane < 16) lsh[slot][lane] = (LSV);                                  \
      _Pragma("unroll") for (int t = 0; t < 4; t++)                            \
        _Pragma("unroll") for (int gg = 0; gg < 4; gg++)                       \
          accs[slot][quad * 4 + gg][t * 16 + r15] = (AC)[t][gg];               \
    }                                                                          \
    __syncthreads();                                                           \
    if (sl < 2) {                                                              \
      const int slot = head * 2 + sl;                                          \
      if (lane < 16) lsh[slot][lane] += (LSV);                                 \
      _Pragma("unroll") for (int t = 0; t < 4; t++)                            \
        _Pragma("unroll") for (int gg = 0; gg < 4; gg++)                       \
          accs[slot][quad * 4 + gg][t * 16 + r15] += (AC)[t][gg];              \
    }                                                                          \
    __syncthreads();                                                           \
    _Pragma("unroll") for (int idx = tid; idx < 4096; idx += 1024) {           \
      int r = idx >> 8, hc = idx & 255;                                        \
      int hh = hc >> 6, col = hc & 63;                                         \
      part[((size_t)half * NN + rb * 32 + (PASS) * 16 + r) * 256 + hc] =       \
          accs[hh * 2][r][col] + accs[hh * 2 + 1][r][col];                     \
    }                                                                          \
    if (tid < 64)                                                              \
      partl[((size_t)half * 4 + (tid >> 4)) * NN + rb * 32 + (PASS) * 16 +     \
            (tid & 15)] = lsh[(tid >> 4) * 2][tid & 15] +                      \
                          lsh[(tid >> 4) * 2 + 1][tid & 15];                   \
    __syncthreads();                                                           \
  } while (0)
  DOPASS(acc0, ls0, 0);
  DOPASS(acc1, ls1, 1);
#undef DOPASS
}

// ---------------- K2-old (fallback if workspace too small for partials)
__global__ __launch_bounds__(1024) void k_att1(
    const unsigned char* __restrict__ bm, const float* __restrict__ ssrc,
    const float* __restrict__ sdst, const short8* __restrict__ Bp,
    unsigned short* __restrict__ x2) {
  const int rb = blockIdx.x;
  const int tid = threadIdx.x;
  const int w = tid >> 6;
  const int head = w & 3;
  const int slice = w >> 2;
  const int lane = tid & 63;
  const int r15 = lane & 15, quad = lane >> 4;
  const int row = rb * 16 + r15;
  const float si = ssrc[head * NN + row];
  const unsigned char* bmrow = bm + (size_t)row * 512;
  const float* sd = sdst + head * NN;
  const short8* Bh = Bp + (size_t)head * 128 * 4 * 64;
  f32x4 acc0 = {0, 0, 0, 0}, acc1 = {0, 0, 0, 0}, acc2 = {0, 0, 0, 0}, acc3 = {0, 0, 0, 0};
  float lsum = 0.f;
  const int kb0 = slice * 32;
  for (int kb = kb0; kb < kb0 + 32; kb++) {
    const int j0 = kb * 32 + quad * 8;
    unsigned int bits = bmrow[kb * 4 + quad];
    float4 q0 = *(const float4*)(sd + j0);
    float4 q1 = *(const float4*)(sd + j0 + 4);
    float sdv[8] = {q0.x, q0.y, q0.z, q0.w, q1.x, q1.y, q1.z, q1.w};
    short8 af;
#pragma unroll
    for (int jj = 0; jj < 8; jj++) {
      float t = si + sdv[jj];
      float lr = fmaxf(t, 0.2f * t);
      float e = __expf(lr);
      float pe = ((bits >> jj) & 1u) ? e : 0.0f;
      lsum += pe;
      af[jj] = (short)f2bf(pe);
    }
    const short8* Bk = Bh + (size_t)kb * 256 + lane;
    short8 b0 = Bk[0], b1 = Bk[64], b2 = Bk[128], b3 = Bk[192];
    acc0 = __builtin_amdgcn_mfma_f32_16x16x32_bf16(af, b0, acc0, 0, 0, 0);
    acc1 = __builtin_amdgcn_mfma_f32_16x16x32_bf16(af, b1, acc1, 0, 0, 0);
    acc2 = __builtin_amdgcn_mfma_f32_16x16x32_bf16(af, b2, acc2, 0, 0, 0);
    acc3 = __builtin_amdgcn_mfma_f32_16x16x32_bf16(af, b3, acc3, 0, 0, 0);
  }
  lsum += __shfl_xor(lsum, 16);
  lsum += __shfl_xor(lsum, 32);
  __shared__ float accs[8][16][66];
  __shared__ float ls[8][16];
  if (slice >= 2) {
    const int slot = w - 8;
    if (lane < 16) ls[slot][lane] = lsum;
#pragma unroll
    for (int g = 0; g < 4; g++) {
      int r = quad * 4 + g;
      accs[slot][r][ 0 + r15] = acc0[g];
      accs[slot][r][16 + r15] = acc1[g];
      accs[slot][r][32 + r15] = acc2[g];
      accs[slot][r][48 + r15] = acc3[g];
    }
  }
  __syncthreads();
  if (slice < 2) {
    const int slot = w;
    if (lane < 16) ls[slot][lane] += lsum;
#pragma unroll
    for (int g = 0; g < 4; g++) {
      int r = quad * 4 + g;
      accs[slot][r][ 0 + r15] += acc0[g];
      accs[slot][r][16 + r15] += acc1[g];
      accs[slot][r][32 + r15] += acc2[g];
      accs[slot][r][48 + r15] += acc3[g];
    }
  }
  __syncthreads();
#pragma unroll
  for (int c = tid; c < 4096; c += 1024) {
    int r = c >> 8, hc = c & 255;
    int hh = hc >> 6, col = hc & 63;
    float s = accs[hh][r][col] + accs[hh + 4][r][col];
    float lt = ls[hh][r] + ls[hh + 4][r];
    float v = (lt > 0.f) ? s / lt : 0.f;
    v = v > 0.f ? v : __expf(v) - 1.f;
    x2[(size_t)(rb * 16 + r) * 256 + hc] = f2bf(v);
  }
}

// ---------------- K3: wo = x2@Wo + bWo. Fused: big path stages directly from
// part/partl (half-sum + normalize + elu inline, x2 round-trip eliminated);
// fallback path (part==nullptr) stages from x2 bf16.
template <typename T>
__device__ __forceinline__ void wo_body(const unsigned short* x2,
    const float* part, const float* partl,
    const T* Wo, const T* bWo, const T* ao_src, const T* ao_dst, const T* ao_b,
    unsigned short* __restrict__ Bp2, float* __restrict__ ssrc2, float* __restrict__ sdst2,
    float (*xs)[260], float (*wp)[16][68], float* av) {
  const int tid = threadIdx.x;
  const int w = tid >> 6, lane = tid & 63;
  const int rg = w & 3, kq = w >> 2;
  const int rb = blockIdx.x;         // 0..255, 16 rows each
  const int d = lane;
  // Phase A: stage x-tile (16 rows x 256) into fp32 LDS
  {
    const int r = tid >> 6, c4 = (tid & 63) * 4;
    const int row = rb * 16 + r;
    if (part) {
      float4 p0 = *(const float4*)(part + (size_t)row * 256 + c4);
      float4 p1 = *(const float4*)(part + (size_t)NN * 256 + (size_t)row * 256 + c4);
      const int head = c4 >> 6;
      float lt = partl[(size_t)head * NN + row] + partl[(size_t)(4 + head) * NN + row];
      float rl = (lt > 0.f) ? 1.f / lt : 0.f;
      float v0 = (p0.x + p1.x) * rl, v1 = (p0.y + p1.y) * rl;
      float v2 = (p0.z + p1.z) * rl, v3 = (p0.w + p1.w) * rl;
      v0 = v0 > 0.f ? v0 : __expf(v0) - 1.f;
      v1 = v1 > 0.f ? v1 : __expf(v1) - 1.f;
      v2 = v2 > 0.f ? v2 : __expf(v2) - 1.f;
      v3 = v3 > 0.f ? v3 : __expf(v3) - 1.f;
      xs[r][c4 + 0] = v0; xs[r][c4 + 1] = v1;
      xs[r][c4 + 2] = v2; xs[r][c4 + 3] = v3;
    } else {
      float hv4[4];
      ld4(x2 + (size_t)row * 256 + c4, hv4);
      xs[r][c4 + 0] = hv4[0]; xs[r][c4 + 1] = hv4[1];
      xs[r][c4 + 2] = hv4[2]; xs[r][c4 + 3] = hv4[3];
    }
  }
  if (tid < 64) av[tid] = ld(ao_src, tid);
  else if (tid < 128) av[tid] = ld(ao_dst, tid - 64);
  __syncthreads();
  const int rr = rg * 4;             // this wave's 4 local rows
  float acc[4];
  float bv = (kq == 0) ? ld(bWo, d) : 0.f;
#pragma unroll
  for (int r = 0; r < 4; r++) acc[r] = bv;
  const int k0 = kq * 64;
  for (int kb = 0; kb < 8; kb++) {
    float wv[8];
#pragma unroll
    for (int j = 0; j < 8; j++)
      wv[j] = ld(Wo, (size_t)(k0 + kb * 8 + j) * 64 + d);
#pragma unroll
    for (int r = 0; r < 4; r++) {
      float4 ha = *(const float4*)(&xs[rr + r][k0 + kb * 8]);
      float4 hb = *(const float4*)(&xs[rr + r][k0 + kb * 8 + 4]);
      acc[r] = fmaf(ha.x, wv[0], acc[r]);
      acc[r] = fmaf(ha.y, wv[1], acc[r]);
      acc[r] = fmaf(ha.z, wv[2], acc[r]);
      acc[r] = fmaf(ha.w, wv[3], acc[r]);
      acc[r] = fmaf(hb.x, wv[4], acc[r]);
      acc[r] = fmaf(hb.y, wv[5], acc[r]);
      acc[r] = fmaf(hb.z, wv[6], acc[r]);
      acc[r] = fmaf(hb.w, wv[7], acc[r]);
    }
  }
  if (kq >= 2) {
#pragma unroll
    for (int r = 0; r < 4; r++) wp[kq - 2][rr + r][d] = acc[r];
  }
  __syncthreads();
  if (kq < 2) {
#pragma unroll
    for (int r = 0; r < 4; r++) wp[kq][rr + r][d] += acc[r];
  }
  __syncthreads();
  if (tid < 128) {
    const int tt = tid >> 5, lnh = tid & 31;
    const int q2 = (rb & 1) * 2 + (lnh >> 4);
    const int ln = q2 * 16 + (lnh & 15);
    const int dd = tt * 16 + (lnh & 15);
    const int rbase = (lnh >> 4) * 8;
    float v[8];
#pragma unroll
    for (int jj = 0; jj < 8; jj++)
      v[jj] = wp[0][rbase + jj][dd] + wp[1][rbase + jj][dd];
    i4s8 s;
    s.i.x = cvtpk(v[0], v[1]); s.i.y = cvtpk(v[2], v[3]);
    s.i.z = cvtpk(v[4], v[5]); s.i.w = cvtpk(v[6], v[7]);
    const int kb = rb >> 1;
    *(int4*)(Bp2 + (((size_t)kb * 4 + tt) * 64 + ln) * 8) = s.i;
  } else if (tid < 144) {
    const int r = tid - 128;
    float ps = 0.f, pd = 0.f;
    for (int c = 0; c < 64; c++) {
      float wv2 = wp[0][r][c] + wp[1][r][c];
      ps = fmaf(wv2, av[c], ps);
      pd = fmaf(wv2, av[64 + c], pd);
    }
    ssrc2[(size_t)rb * 16 + r] = ps + ld(ao_b, 0);
    sdst2[(size_t)rb * 16 + r] = pd;
  }
}
__global__ __launch_bounds__(1024, 4) void k_wo(const unsigned short* __restrict__ x2,
    const float* __restrict__ part, const float* __restrict__ partl,
    const void* Wo, const void* bWo, const void* ao_src, const void* ao_dst, const void* ao_b,
    const int* __restrict__ flags, unsigned short* Bp2, float* ssrc2, float* sdst2) {
  __shared__ float xs[16][260];
  __shared__ float wp[2][16][68];
  __shared__ float av[128];
  if (flags[0])
    wo_body<unsigned short>(x2, part, partl, (const unsigned short*)Wo,
        (const unsigned short*)bWo, (const unsigned short*)ao_src,
        (const unsigned short*)ao_dst, (const unsigned short*)ao_b,
        Bp2, ssrc2, sdst2, xs, wp, av);
  else
    wo_body<float>(x2, part, partl, (const float*)Wo, (const float*)bWo,
        (const float*)ao_src, (const float*)ao_dst, (const float*)ao_b,
        Bp2, ssrc2, sdst2, xs, wp, av);
}

// ---------------- K4: layer-2 attention (1 head), 16 rows/block, 16-way j-split.
__global__ __launch_bounds__(1024) void k_att2(
    const unsigned char* __restrict__ bm, const float* __restrict__ ssrc,
    const float* __restrict__ sdst, const short8* __restrict__ Bp,
    const int* __restrict__ flags, void* __restrict__ outv) {
  const int rb = blockIdx.x;
  const int tid = threadIdx.x;
  const int w = tid >> 6;  // j-slice 0..15
  const int lane = tid & 63;
  const int r15 = lane & 15, quad = lane >> 4;
  const int row = rb * 16 + r15;
  const float si = ssrc[row];
  const unsigned char* bmrow = bm + (size_t)row * 512;
  f32x4 acc0 = {0, 0, 0, 0}, acc1 = {0, 0, 0, 0}, acc2 = {0, 0, 0, 0}, acc3 = {0, 0, 0, 0};
  float lsum = 0.f;
  const int kb0 = w * 8;
#pragma unroll
  for (int g = 0; g < 2; g++) {
    int4 ubm = *(const int4*)(bmrow + (kb0 + g * 4) * 4);
    int wds[4] = {ubm.x, ubm.y, ubm.z, ubm.w};
#pragma unroll
    for (int kk = 0; kk < 4; kk++) {
      const int kb = kb0 + g * 4 + kk;
      const int j0 = kb * 32 + quad * 8;
      unsigned int bits = (((unsigned int)wds[kk]) >> (quad * 8)) & 0xffu;
      float4 q0 = *(const float4*)(sdst + j0);
      float4 q1 = *(const float4*)(sdst + j0 + 4);
      float sdv[8] = {q0.x, q0.y, q0.z, q0.w, q1.x, q1.y, q1.z, q1.w};
      float pe[8];
#pragma unroll
      for (int jj = 0; jj < 8; jj++) {
        float t = si + sdv[jj];
        float e = __expf(fmaxf(t, 0.2f * t));
        pe[jj] = ((bits >> jj) & 1u) ? e : 0.f;
        lsum += pe[jj];
      }
      i4s8 a;
      a.i.x = cvtpk(pe[0], pe[1]); a.i.y = cvtpk(pe[2], pe[3]);
      a.i.z = cvtpk(pe[4], pe[5]); a.i.w = cvtpk(pe[6], pe[7]);
      const short8* Bk = Bp + (size_t)kb * 256 + lane;
      short8 b0 = Bk[0], b1 = Bk[64], b2 = Bk[128], b3 = Bk[192];
      acc0 = __builtin_amdgcn_mfma_f32_16x16x32_bf16(a.s, b0, acc0, 0, 0, 0);
      acc1 = __builtin_amdgcn_mfma_f32_16x16x32_bf16(a.s, b1, acc1, 0, 0, 0);
      acc2 = __builtin_amdgcn_mfma_f32_16x16x32_bf16(a.s, b2, acc2, 0, 0, 0);
      acc3 = __builtin_amdgcn_mfma_f32_16x16x32_bf16(a.s, b3, acc3, 0, 0, 0);
    }
  }
  lsum += __shfl_xor(lsum, 16);
  lsum += __shfl_xor(lsum, 32);
  __shared__ float accs[8][16][66];
  __shared__ float ls2[8][16];
  if (w >= 8) {
    const int slot = w - 8;
    if (lane < 16) ls2[slot][lane] = lsum;
#pragma unroll
    for (int g = 0; g < 4; g++) {
      int r = quad * 4 + g;
      accs[slot][r][ 0 + r15] = acc0[g];
      accs[slot][r][16 + r15] = acc1[g];
      accs[slot][r][32 + r15] = acc2[g];
      accs[slot][r][48 + r15] = acc3[g];
    }
  }
  __syncthreads();
  if (w < 8) {
    const int slot = w;
    if (lane < 16) ls2[slot][lane] += lsum;
#pragma unroll
    for (int g = 0; g < 4; g++) {
      int r = quad * 4 + g;
      accs[slot][r][ 0 + r15] += acc0[g];
      accs[slot][r][16 + r15] += acc1[g];
      accs[slot][r][32 + r15] += acc2[g];
      accs[slot][r][48 + r15] += acc3[g];
    }
  }
  __syncthreads();
  {
    const int r = tid >> 6, col = tid & 63;
    float s = 0.f, lt = 0.f;
#pragma unroll
    for (int k = 0; k < 8; k++) { s += accs[k][r][col]; lt += ls2[k][r]; }
    float v = (lt > 0.f) ? s / lt : 0.f;
    v = v > 0.f ? v : __expf(v) - 1.f;
    size_t idx = (size_t)(rb * 16 + r) * 64 + col;
    if (flags[0]) ((unsigned short*)outv)[idx] = f2bf(v);
    else          ((float*)outv)[idx] = v;
  }
}

extern "C" void kernel_launch(void* const* d_in, const int* in_sizes, int n_in,
                              void* d_out, int out_size, void* d_ws, size_t ws_size,
                              hipStream_t stream) {
  const void* h      = d_in[0];
  const void* adj    = d_in[1];
  const void* Wh     = d_in[2];
  const void* bWh    = d_in[3];
  const void* a_src  = d_in[4];
  const void* a_dst  = d_in[5];
  const void* a_b    = d_in[6];
  const void* Wo     = d_in[7];
  const void* bWo    = d_in[8];
  const void* ao_src = d_in[9];
  const void* ao_dst = d_in[10];
  const void* ao_b   = d_in[11];

  size_t need_old = 16 + (size_t)NN * 512 + (size_t)NHEADS * NN * HID * 2 +
                    (size_t)NN * 256 * 2 + (size_t)NN * 64 * 2 +
                    (size_t)NHEADS * NN * 8 + (size_t)NN * 8;
  size_t need_new = need_old + (size_t)2 * NN * 256 * 4 + (size_t)2 * 4 * NN * 4;
  if (ws_size < need_old) {
    // Distinct signature if workspace is too small (bf16 0x4545 = 789).
    hipMemsetAsync(d_out, 0x45, (size_t)out_size * 2, stream);
    return;
  }
  const bool big = ws_size >= need_new;
  unsigned char* ws = (unsigned char*)d_ws;
  int* flags = (int*)ws;                        ws += 16;
  unsigned char* bmp = ws;                      ws += (size_t)NN * 512;               // 2 MB
  unsigned short* Bp1 = (unsigned short*)ws;    ws += (size_t)NHEADS * NN * HID * 2;  // 2 MB
  unsigned short* x2  = (unsigned short*)ws;    ws += (size_t)NN * 256 * 2;           // 2 MB
  unsigned short* Bp2 = (unsigned short*)ws;    ws += (size_t)NN * 64 * 2;            // 512 KB
  float* ssrc1 = (float*)ws;                    ws += (size_t)NHEADS * NN * 4;
  float* sdst1 = (float*)ws;                    ws += (size_t)NHEADS * NN * 4;
  float* ssrc2 = (float*)ws;                    ws += (size_t)NN * 4;
  float* sdst2 = (float*)ws;                    ws += (size_t)NN * 4;
  float* part  = (float*)ws;                    ws += (size_t)2 * NN * 256 * 4;       // 8 MB
  float* partl = (float*)ws;                    ws += (size_t)2 * 4 * NN * 4;         // 128 KB

  k_bm   <<<dim3(4096), dim3(256),  0, stream>>>(adj, h, flags, bmp);
  k_wh   <<<dim3(256),  dim3(1024), 0, stream>>>(h, Wh, bWh, a_src, a_dst, a_b, flags,
                                                 Bp1, ssrc1, sdst1);
  if (big) {
    k_att1s<<<dim3(256), dim3(1024), 0, stream>>>(bmp, ssrc1, sdst1, (const short8*)Bp1,
                                                  part, partl);
    k_wo   <<<dim3(256), dim3(1024), 0, stream>>>(x2, part, partl, Wo, bWo, ao_src, ao_dst,
                                                  ao_b, flags, Bp2, ssrc2, sdst2);
  } else {
    k_att1 <<<dim3(256), dim3(1024), 0, stream>>>(bmp, ssrc1, sdst1, (const short8*)Bp1, x2);
    k_wo   <<<dim3(256), dim3(1024), 0, stream>>>(x2, (const float*)nullptr,
                                                  (const float*)nullptr, Wo, bWo, ao_src,
                                                  ao_dst, ao_b, flags, Bp2, ssrc2, sdst2);
  }
  k_att2 <<<dim3(256),  dim3(1024), 0, stream>>>(bmp, ssrc2, sdst2, (const short8*)Bp2,
                                                 flags, d_out);
}